// Round 1
// baseline (4143.791 us; speedup 1.0000x reference)
//
#include <hip/hip_runtime.h>
#include <math.h>

// ---------------------------------------------------------------------------
// PhysicsInformedCMBNet: 5 convs (training-mode BN -> batch stats) + maxpools,
// FFT radial power-spectrum branch, MLP heads. fp32 throughout (round 0).
// Conv biases are mathematically dropped: BN(x + c) == BN(x) for per-channel
// constant c (training-mode BN subtracts the batch mean).
// ---------------------------------------------------------------------------

#define PI2F 6.283185307179586f

__device__ __forceinline__ int bitrev8(int x) {
  x = ((x & 0x0F) << 4) | ((x >> 4) & 0x0F);
  x = ((x & 0x33) << 2) | ((x >> 2) & 0x33);
  x = ((x & 0x55) << 1) | ((x >> 1) & 0x55);
  return x;
}

// In-LDS 256-point radix-2 DIT FFT; 64 threads (one wave), s[] pre-bit-reversed.
__device__ __forceinline__ void fft256(float2* s, int t) {
  #pragma unroll
  for (int st = 1; st <= 8; ++st) {
    int half = 1 << (st - 1);
    float w0 = -PI2F / (float)(1 << st);
    #pragma unroll
    for (int j = 0; j < 2; ++j) {
      int bf = t + (j << 6);            // 0..127
      int pos = bf & (half - 1);
      int grp = bf >> (st - 1);
      int i0 = (grp << st) | pos;
      int i1 = i0 + half;
      float sn, cs;
      sincosf(w0 * (float)pos, &sn, &cs);
      float2 a = s[i0], b = s[i1];
      float tr = cs * b.x - sn * b.y;
      float ti = cs * b.y + sn * b.x;
      s[i0] = make_float2(a.x + tr, a.y + ti);
      s[i1] = make_float2(a.x - tr, a.y - ti);
    }
    __syncthreads();
  }
}

__global__ __launch_bounds__(64)
void fft_rows(const float* __restrict__ x, float2* __restrict__ out) {
  __shared__ float2 s[256];
  int blk = blockIdx.x;                 // b*256 + row
  const float* rowp = x + (size_t)blk * 256;
  int t = threadIdx.x;
  #pragma unroll
  for (int e = 0; e < 4; ++e) {
    int i = t + (e << 6);
    s[bitrev8(i)] = make_float2(rowp[i], 0.f);
  }
  __syncthreads();
  fft256(s, t);
  float2* op = out + (size_t)blk * 256;
  #pragma unroll
  for (int e = 0; e < 4; ++e) { int i = t + (e << 6); op[i] = s[i]; }
}

// exact radial bin: j such that 16*j^2 <= r2 < 16*(j+1)^2  (bins of width 4)
__device__ __forceinline__ int radial_bin(int r2) {
  int j = (int)(sqrtf((float)r2) * 0.25f);
  while ((j + 1) * (j + 1) * 16 <= r2) ++j;
  while (j > 0 && j * j * 16 > r2) --j;
  return j;
}

__global__ __launch_bounds__(64)
void fft_cols_radial(const float2* __restrict__ f, float* __restrict__ radial) {
  __shared__ float2 s[256];
  __shared__ float bins[32];
  int b = blockIdx.x >> 8;
  int col = blockIdx.x & 255;
  int t = threadIdx.x;
  const float2* base = f + (size_t)b * 65536 + col;
  #pragma unroll
  for (int e = 0; e < 4; ++e) {
    int i = t + (e << 6);
    s[bitrev8(i)] = base[(size_t)i * 256];
  }
  if (t < 32) bins[t] = 0.f;
  __syncthreads();
  fft256(s, t);
  #pragma unroll
  for (int e = 0; e < 4; ++e) {
    int i = t + (e << 6);
    float2 v = s[i];
    float ps = v.x * v.x + v.y * v.y;
    int dy = i - 128, dx = col - 128;
    int r2 = dx * dx + dy * dy;
    if (r2 < 16384) atomicAdd(&bins[radial_bin(r2)], ps);
  }
  __syncthreads();
  if (t < 32) atomicAdd(&radial[b * 32 + t], bins[t]);
}

__global__ __launch_bounds__(256)
void radial_finalize(const float* __restrict__ radial, float* __restrict__ pf0) {
  __shared__ int cnt[32];
  int b = blockIdx.x, t = threadIdx.x;
  if (t < 32) cnt[t] = 0;
  __syncthreads();
  int dy = t - 128;
  for (int k = 0; k < 256; ++k) {
    int dx = k - 128;
    int r2 = dx * dx + dy * dy;
    if (r2 < 16384) atomicAdd(&cnt[radial_bin(r2)], 1);
  }
  __syncthreads();
  if (t < 32) {
    float c = (float)cnt[t];
    float sum = radial[b * 32 + t];
    float val = c > 0.f ? sum / fmaxf(c, 1.f) : 0.f;
    pf0[b * 32 + t] = logf(val + 1e-10f);
  }
}

// ---------------- conv1 (Cin=1, 5x5, recompute-for-stats) -------------------

__global__ __launch_bounds__(256)
void conv1_stats(const float* __restrict__ x, const float* __restrict__ w,
                 float* __restrict__ stats) {
  int t = threadIdx.x;
  int y = blockIdx.x;                  // one row per block
  int co = blockIdx.y, n = blockIdx.z;
  const float* xp = x + (size_t)n * 65536;
  const float* wp = w + co * 25;
  float acc = 0.f;
  #pragma unroll
  for (int ky = 0; ky < 5; ++ky) {
    int iy = y + ky - 2;
    if (iy >= 0 && iy < 256) {
      #pragma unroll
      for (int kx = 0; kx < 5; ++kx) {
        int ix = t + kx - 2;
        float v = (ix >= 0 && ix < 256) ? xp[iy * 256 + ix] : 0.f;
        acc += v * wp[ky * 5 + kx];
      }
    }
  }
  float s1 = acc, s2 = acc * acc;
  #pragma unroll
  for (int off = 32; off > 0; off >>= 1) {
    s1 += __shfl_down(s1, off);
    s2 += __shfl_down(s2, off);
  }
  __shared__ float r1[4], r2[4];
  int wid = t >> 6;
  if ((t & 63) == 0) { r1[wid] = s1; r2[wid] = s2; }
  __syncthreads();
  if (t == 0) {
    atomicAdd(&stats[co],      r1[0] + r1[1] + r1[2] + r1[3]);
    atomicAdd(&stats[32 + co], r2[0] + r2[1] + r2[2] + r2[3]);
  }
}

__global__ __launch_bounds__(256)
void conv1_apply(const float* __restrict__ x, const float* __restrict__ w,
                 const float* __restrict__ stats, const float* __restrict__ g,
                 const float* __restrict__ bb, float* __restrict__ out) {
  int t = threadIdx.x;
  int p = blockIdx.x * 256 + t;        // pooled pixel 0..16383
  int py = p >> 7, px = p & 127;
  int co = blockIdx.y, n = blockIdx.z;
  const float* xp = x + (size_t)n * 65536;
  const float* wp = w + co * 25;
  float mean = stats[co] * (1.f / 1048576.f);
  float var  = stats[32 + co] * (1.f / 1048576.f) - mean * mean;
  float sc = g[co] / sqrtf(var + 1e-5f);
  float sh = bb[co] - mean * sc;
  float best = -1e30f;
  #pragma unroll
  for (int sy = 0; sy < 2; ++sy) {
    #pragma unroll
    for (int sx = 0; sx < 2; ++sx) {
      int y = py * 2 + sy, xc = px * 2 + sx;
      float acc = 0.f;
      #pragma unroll
      for (int ky = 0; ky < 5; ++ky) {
        int iy = y + ky - 2;
        if (iy < 0 || iy > 255) continue;
        #pragma unroll
        for (int kx = 0; kx < 5; ++kx) {
          int ix = xc + kx - 2;
          float v = (ix >= 0 && ix < 256) ? xp[iy * 256 + ix] : 0.f;
          acc += v * wp[ky * 5 + kx];
        }
      }
      best = fmaxf(best, acc * sc + sh);
    }
  }
  out[(((size_t)n * 32 + co) << 14) + p] = fmaxf(best, 0.f);
}

// ---------------- generic tiled direct conv (KxK, pad=K/2) ------------------
// Block: 256 threads = (TLX/4) x TLY; each thread -> COB channels x 4 pixels.
// Weights staged in LDS as [ci][ky][kx][co] so a float4 read gives COB values.

template <int K, int TLY, int TLX, int CIB, int COB>
__global__ __launch_bounds__(256)
void conv_tiled(const float* __restrict__ in, const float* __restrict__ w,
                float* __restrict__ out, int Cin, int Cout, int H, int W) {
  constexpr int PAD = K / 2;
  constexpr int PX = 4;
  constexpr int TXT = TLX / PX;
  constexpr int TLXP = TLX + 4;        // >= TLX+K-1 and >= (TXT-1)*PX+8
  constexpr int TLYP = TLY + K - 1;
  constexpr int KK = K * K;
  static_assert(TXT * TLY == 256, "block must be 256 threads");
  static_assert(COB == 4, "weight float4 read assumes COB==4");
  __shared__ alignas(16) float tile[CIB][TLYP][TLXP];
  __shared__ alignas(16) float wls[CIB][K][K][COB];

  int t = threadIdx.x;
  int tx = t % TXT, ty = t / TXT;
  int tilesX = W / TLX;
  int tX = (blockIdx.x % tilesX) * TLX;
  int tY = (blockIdx.x / tilesX) * TLY;
  int coB = blockIdx.y * COB;
  int n = blockIdx.z;

  float acc[COB][PX];
  #pragma unroll
  for (int c = 0; c < COB; ++c)
    #pragma unroll
    for (int p = 0; p < PX; ++p) acc[c][p] = 0.f;

  const float* inb = in + (size_t)n * Cin * H * W;

  for (int cc = 0; cc < Cin; cc += CIB) {
    constexpr int TN = CIB * TLYP * TLXP;
    for (int idx = t; idx < TN; idx += 256) {
      int ci = idx / (TLYP * TLXP);
      int rem = idx % (TLYP * TLXP);
      int ly = rem / TLXP, lx = rem % TLXP;
      int iy = tY + ly - PAD, ix = tX + lx - PAD;
      float v = 0.f;
      if (iy >= 0 && iy < H && ix >= 0 && ix < W)
        v = inb[((size_t)(cc + ci) * H + iy) * W + ix];
      tile[ci][ly][lx] = v;
    }
    constexpr int WN = CIB * KK * COB;
    for (int idx = t; idx < WN; idx += 256) {
      int co = idx % COB;
      int r = idx / COB;
      int kx = r % K; r /= K;
      int ky = r % K; int ci = r / K;
      wls[ci][ky][kx][co] =
          w[((size_t)(coB + co) * Cin + cc + ci) * KK + ky * K + kx];
    }
    __syncthreads();

    #pragma unroll
    for (int ci = 0; ci < CIB; ++ci) {
      #pragma unroll
      for (int ky = 0; ky < K; ++ky) {
        const float* row = &tile[ci][ty + ky][tx * PX];
        float4 r0 = *(const float4*)(row);
        float4 r1 = *(const float4*)(row + 4);
        float r[8] = {r0.x, r0.y, r0.z, r0.w, r1.x, r1.y, r1.z, r1.w};
        #pragma unroll
        for (int kx = 0; kx < K; ++kx) {
          float4 wv = *(const float4*)(&wls[ci][ky][kx][0]);
          float wa[4] = {wv.x, wv.y, wv.z, wv.w};
          #pragma unroll
          for (int co = 0; co < COB; ++co)
            #pragma unroll
            for (int p = 0; p < PX; ++p)
              acc[co][p] += r[p + kx] * wa[co];
        }
      }
    }
    __syncthreads();
  }

  int yy = tY + ty, xx0 = tX + tx * PX;
  float* ob = out + (((size_t)n * Cout + coB) * H + yy) * W + xx0;
  #pragma unroll
  for (int co = 0; co < COB; ++co) {
    float4 v = make_float4(acc[co][0], acc[co][1], acc[co][2], acc[co][3]);
    *(float4*)(ob + (size_t)co * H * W) = v;
  }
}

// ---------------- BN stats / apply ------------------------------------------

__global__ __launch_bounds__(256)
void bn_stats(const float* __restrict__ x, float* __restrict__ stats,
              int C, int HW) {
  int c = blockIdx.x, n = blockIdx.y;
  const float4* p = (const float4*)(x + ((size_t)n * C + c) * HW);
  int nv = HW >> 2;
  float s1 = 0.f, s2 = 0.f;
  for (int i = threadIdx.x; i < nv; i += 256) {
    float4 v = p[i];
    s1 += v.x + v.y + v.z + v.w;
    s2 += v.x * v.x + v.y * v.y + v.z * v.z + v.w * v.w;
  }
  #pragma unroll
  for (int off = 32; off > 0; off >>= 1) {
    s1 += __shfl_down(s1, off);
    s2 += __shfl_down(s2, off);
  }
  __shared__ float r1[4], r2[4];
  int wid = threadIdx.x >> 6;
  if ((threadIdx.x & 63) == 0) { r1[wid] = s1; r2[wid] = s2; }
  __syncthreads();
  if (threadIdx.x == 0) {
    atomicAdd(&stats[c],     r1[0] + r1[1] + r1[2] + r1[3]);
    atomicAdd(&stats[C + c], r2[0] + r2[1] + r2[2] + r2[3]);
  }
}

__global__ __launch_bounds__(256)
void bn_relu_maxpool(const float* __restrict__ x, const float* __restrict__ stats,
                     const float* __restrict__ g, const float* __restrict__ bb,
                     float* __restrict__ out, int C_buf, int C_out, int c_off,
                     int H, int W, float invNHW) {
  int c = blockIdx.x, n = blockIdx.y;
  float mean = stats[c] * invNHW;
  float var  = stats[C_buf + c] * invNHW - mean * mean;
  float sc = g[c] / sqrtf(var + 1e-5f);
  float sh = bb[c] - mean * sc;
  int PH = H >> 1, PW = W >> 1;
  const float* xp = x + ((size_t)n * C_buf + c) * H * W;
  float* op = out + ((size_t)n * C_out + c_off + c) * PH * PW;
  for (int i = threadIdx.x; i < PH * PW; i += 256) {
    int py = i / PW, px = i - py * PW;
    const float* r0 = xp + (py * 2) * W + px * 2;
    float a = fmaxf(r0[0] * sc + sh, 0.f);
    float b = fmaxf(r0[1] * sc + sh, 0.f);
    float d = fmaxf(r0[W] * sc + sh, 0.f);
    float e = fmaxf(r0[W + 1] * sc + sh, 0.f);
    op[i] = fmaxf(fmaxf(a, b), fmaxf(d, e));
  }
}

__global__ __launch_bounds__(256)
void bn_relu(const float* __restrict__ x, const float* __restrict__ stats,
             const float* __restrict__ g, const float* __restrict__ bb,
             float* __restrict__ out, int C, int HW, float invNHW) {
  int c = blockIdx.x, n = blockIdx.y;
  float mean = stats[c] * invNHW;
  float var  = stats[C + c] * invNHW - mean * mean;
  float sc = g[c] / sqrtf(var + 1e-5f);
  float sh = bb[c] - mean * sc;
  const float4* xp = (const float4*)(x + ((size_t)n * C + c) * HW);
  float4* op = (float4*)(out + ((size_t)n * C + c) * HW);
  int nv = HW >> 2;
  for (int i = threadIdx.x; i < nv; i += 256) {
    float4 v = xp[i];
    v.x = fmaxf(v.x * sc + sh, 0.f);
    v.y = fmaxf(v.y * sc + sh, 0.f);
    v.z = fmaxf(v.z * sc + sh, 0.f);
    v.w = fmaxf(v.w * sc + sh, 0.f);
    op[i] = v;
  }
}

// pconv: BN + ReLU + 8x8 avgpool -> concat[b][c*16 + opix]  (C=128, H=W=32)
__global__ __launch_bounds__(64)
void bn_relu_avgpool(const float* __restrict__ x, const float* __restrict__ stats,
                     const float* __restrict__ g, const float* __restrict__ bb,
                     float* __restrict__ concat, float invNHW) {
  int c = blockIdx.x, n = blockIdx.y;
  int t = threadIdx.x;
  if (t >= 16) return;
  float mean = stats[c] * invNHW;
  float var  = stats[128 + c] * invNHW - mean * mean;
  float sc = g[c] / sqrtf(var + 1e-5f);
  float sh = bb[c] - mean * sc;
  int py = t >> 2, px = t & 3;
  const float* xp = x + ((size_t)n * 128 + c) * 1024 + py * 8 * 32 + px * 8;
  float s = 0.f;
  #pragma unroll
  for (int yy = 0; yy < 8; ++yy)
    #pragma unroll
    for (int xx = 0; xx < 8; ++xx)
      s += fmaxf(xp[yy * 32 + xx] * sc + sh, 0.f);
  concat[(size_t)n * 2112 + c * 16 + t] = s * (1.f / 64.f);
}

// ---------------- linear (one wave per output element) ----------------------

__global__ __launch_bounds__(64)
void linear_k(const float* __restrict__ in, const float* __restrict__ w,
              const float* __restrict__ bias, float* __restrict__ out,
              int I, int in_stride, int out_stride, int relu) {
  int o = blockIdx.x, b = blockIdx.y;
  int lane = threadIdx.x;
  const float* ip = in + (size_t)b * in_stride;
  const float* wp = w + (size_t)o * I;
  float acc = 0.f;
  for (int i = lane; i < I; i += 64) acc += ip[i] * wp[i];
  #pragma unroll
  for (int off = 32; off > 0; off >>= 1) acc += __shfl_down(acc, off);
  if (lane == 0) {
    float v = acc + bias[o];
    if (relu) v = fmaxf(v, 0.f);
    out[(size_t)b * out_stride + o] = v;
  }
}

// ---------------------------------------------------------------------------

extern "C" void kernel_launch(void* const* d_in, const int* in_sizes, int n_in,
                              void* d_out, int out_size, void* d_ws, size_t ws_size,
                              hipStream_t stream) {
  (void)in_sizes; (void)n_in; (void)out_size; (void)ws_size;
  const float* x   = (const float*)d_in[0];
  const float* cw1 = (const float*)d_in[1];
  const float* g1  = (const float*)d_in[3];
  const float* bb1 = (const float*)d_in[4];
  const float* cw2 = (const float*)d_in[5];
  const float* g2  = (const float*)d_in[7];
  const float* bb2 = (const float*)d_in[8];
  const float* cw3 = (const float*)d_in[9];
  const float* g3  = (const float*)d_in[11];
  const float* bb3 = (const float*)d_in[12];
  const float* cw4 = (const float*)d_in[13];
  const float* g4  = (const float*)d_in[15];
  const float* bb4 = (const float*)d_in[16];
  const float* pcw = (const float*)d_in[17];
  const float* pg  = (const float*)d_in[19];
  const float* pbb = (const float*)d_in[20];
  const float* pw1 = (const float*)d_in[21];
  const float* pb1 = (const float*)d_in[22];
  const float* pw2 = (const float*)d_in[23];
  const float* pb2 = (const float*)d_in[24];
  const float* pw3 = (const float*)d_in[25];
  const float* pb3 = (const float*)d_in[26];
  const float* fw1 = (const float*)d_in[27];
  const float* fb1 = (const float*)d_in[28];
  const float* fw2 = (const float*)d_in[29];
  const float* fb2 = (const float*)d_in[30];
  const float* fw3 = (const float*)d_in[31];
  const float* fb3 = (const float*)d_in[32];
  const float* fw4 = (const float*)d_in[33];
  const float* fb4 = (const float*)d_in[34];

  float* ws = (float*)d_ws;
  // Regions (float offsets). Total ~92.5 MB.
  const size_t R0 = 0;                      // 8,388,608: pool1 -> conv3 out
  const size_t R1 = R0 + 8388608;           // 8,388,608: fft -> conv2 half -> conv4act+pconvout
  const size_t R2 = R1 + 8388608;           // 4,194,304: pool2 -> conv4 out
  const size_t R3 = R2 + 4194304;           // 2,097,152: pool3
  size_t o = R3 + 2097152;
  float* zbase  = ws + o;                   // zero-init block (stats + radial)
  float* stats1 = zbase;                    // 64
  float* stats2 = zbase + 64;               // 128 (two 64-float halves)
  float* stats3 = zbase + 192;              // 256
  float* stats4 = zbase + 448;              // 512
  float* stats5 = zbase + 960;              // 256
  float* radial = zbase + 1216;             // 512
  o += 1728;
  float* pf0    = ws + o; o += 16 * 32;
  float* pf1    = ws + o; o += 16 * 256;
  float* pf2    = ws + o; o += 16 * 128;
  float* concat = ws + o; o += 16 * 2112;
  float* fc1o   = ws + o; o += 16 * 512;
  float* fc2o   = ws + o; o += 16 * 256;
  float* fc3o   = ws + o; o += 16 * 128;

  hipMemsetAsync(zbase, 0, 1728 * sizeof(float), stream);

  // ---- FFT / power-features branch (uses R1 before convs touch it) ----
  float2* fftbuf = (float2*)(ws + R1);
  fft_rows<<<4096, 64, 0, stream>>>(x, fftbuf);
  fft_cols_radial<<<4096, 64, 0, stream>>>(fftbuf, radial);
  radial_finalize<<<16, 256, 0, stream>>>(radial, pf0);
  linear_k<<<dim3(256, 16), 64, 0, stream>>>(pf0, pw1, pb1, pf1, 32, 32, 256, 1);
  linear_k<<<dim3(128, 16), 64, 0, stream>>>(pf1, pw2, pb2, pf2, 256, 256, 128, 1);
  linear_k<<<dim3(64, 16), 64, 0, stream>>>(pf2, pw3, pb3, concat + 2048, 128, 128, 2112, 1);

  // ---- conv1 (recompute for stats; fused BN+ReLU+maxpool) ----
  conv1_stats<<<dim3(256, 32, 16), 256, 0, stream>>>(x, cw1, stats1);
  conv1_apply<<<dim3(64, 32, 16), 256, 0, stream>>>(x, cw1, stats1, g1, bb1, ws + R0);

  // ---- conv2 in two Cout halves (exact: BN stats are per-channel) ----
  for (int h = 0; h < 2; ++h) {
    conv_tiled<5, 16, 64, 4, 4><<<dim3(16, 8, 16), 256, 0, stream>>>(
        ws + R0, cw2 + (size_t)h * 32 * 32 * 25, ws + R1, 32, 32, 128, 128);
    bn_stats<<<dim3(32, 16), 256, 0, stream>>>(ws + R1, stats2 + h * 64, 32, 16384);
    bn_relu_maxpool<<<dim3(32, 16), 256, 0, stream>>>(
        ws + R1, stats2 + h * 64, g2 + h * 32, bb2 + h * 32, ws + R2,
        32, 64, h * 32, 128, 128, 1.f / 262144.f);
  }

  // ---- conv3 ----
  conv_tiled<3, 16, 64, 4, 4><<<dim3(4, 32, 16), 256, 0, stream>>>(
      ws + R2, cw3, ws + R0, 64, 128, 64, 64);
  bn_stats<<<dim3(128, 16), 256, 0, stream>>>(ws + R0, stats3, 128, 4096);
  bn_relu_maxpool<<<dim3(128, 16), 256, 0, stream>>>(
      ws + R0, stats3, g3, bb3, ws + R3, 128, 128, 0, 64, 64, 1.f / 65536.f);

  // ---- conv4 ----
  conv_tiled<3, 32, 32, 4, 4><<<dim3(1, 64, 16), 256, 0, stream>>>(
      ws + R3, cw4, ws + R2, 128, 256, 32, 32);
  bn_stats<<<dim3(256, 16), 256, 0, stream>>>(ws + R2, stats4, 256, 1024);
  bn_relu<<<dim3(256, 16), 256, 0, stream>>>(
      ws + R2, stats4, g4, bb4, ws + R1, 256, 1024, 1.f / 16384.f);

  // ---- pconv ----
  conv_tiled<3, 32, 32, 4, 4><<<dim3(1, 32, 16), 256, 0, stream>>>(
      ws + R1, pcw, ws + R1 + 4194304, 256, 128, 32, 32);
  bn_stats<<<dim3(128, 16), 256, 0, stream>>>(ws + R1 + 4194304, stats5, 128, 1024);
  bn_relu_avgpool<<<dim3(128, 16), 64, 0, stream>>>(
      ws + R1 + 4194304, stats5, pg, pbb, concat, 1.f / 16384.f);

  // ---- classifier head ----
  linear_k<<<dim3(512, 16), 64, 0, stream>>>(concat, fw1, fb1, fc1o, 2112, 2112, 512, 1);
  linear_k<<<dim3(256, 16), 64, 0, stream>>>(fc1o, fw2, fb2, fc2o, 512, 512, 256, 1);
  linear_k<<<dim3(128, 16), 64, 0, stream>>>(fc2o, fw3, fb3, fc3o, 256, 256, 128, 1);
  linear_k<<<dim3(2, 16), 64, 0, stream>>>(fc3o, fw4, fb4, (float*)d_out, 128, 128, 2, 0);
}

// Round 2
// 858.443 us; speedup vs baseline: 4.8271x; 4.8271x over previous
//
#include <hip/hip_runtime.h>
#include <math.h>

// ---------------------------------------------------------------------------
// R2: convs 2-5 as implicit-GEMM MFMA (f16 inputs, fp32 accum), NHWC f16
// activations, weights pre-transformed to [tap][co][ci] f16. conv1 + FFT +
// BN stats/apply + FC head in fp32. Conv biases dropped (BN absorbs them).
// MFMA 16x16x32 f16 layouts (guide-verified family):
//   A: m=lane&15, k=(lane>>4)*8+j   B: n=lane&15, k=(lane>>4)*8+j
//   D: col=lane&15, row=(lane>>4)*4+reg
// ---------------------------------------------------------------------------

#define PI2F 6.283185307179586f

typedef _Float16 half8 __attribute__((ext_vector_type(8)));
typedef float f32x4 __attribute__((ext_vector_type(4)));

// ---------------- FFT branch ------------------------------------------------

__device__ __forceinline__ int bitrev8(int x) {
  x = ((x & 0x0F) << 4) | ((x >> 4) & 0x0F);
  x = ((x & 0x33) << 2) | ((x >> 2) & 0x33);
  x = ((x & 0x55) << 1) | ((x >> 1) & 0x55);
  return x;
}

__device__ __forceinline__ void fill_tw(float2* tw, int t) {
  for (int i = t; i < 128; i += 64) {
    float sn, cs;
    sincosf(-(PI2F / 256.f) * (float)i, &sn, &cs);
    tw[i] = make_float2(cs, sn);
  }
}

__device__ __forceinline__ void fft256(float2* s, const float2* tw, int t) {
  #pragma unroll
  for (int st = 1; st <= 8; ++st) {
    int half = 1 << (st - 1);
    #pragma unroll
    for (int j = 0; j < 2; ++j) {
      int bf = t + (j << 6);
      int pos = bf & (half - 1);
      int grp = bf >> (st - 1);
      int i0 = (grp << st) | pos;
      int i1 = i0 + half;
      int k = pos << (8 - st);
      float cs = tw[k].x, sn = tw[k].y;
      float2 a = s[i0], b = s[i1];
      float tr = cs * b.x - sn * b.y;
      float ti = cs * b.y + sn * b.x;
      s[i0] = make_float2(a.x + tr, a.y + ti);
      s[i1] = make_float2(a.x - tr, a.y - ti);
    }
    __syncthreads();
  }
}

__global__ __launch_bounds__(64)
void fft_rows(const float* __restrict__ x, float2* __restrict__ out) {
  __shared__ float2 s[256];
  __shared__ float2 tw[128];
  int blk = blockIdx.x;
  const float* rowp = x + (size_t)blk * 256;
  int t = threadIdx.x;
  fill_tw(tw, t);
  #pragma unroll
  for (int e = 0; e < 4; ++e) {
    int i = t + (e << 6);
    s[bitrev8(i)] = make_float2(rowp[i], 0.f);
  }
  __syncthreads();
  fft256(s, tw, t);
  float2* op = out + (size_t)blk * 256;
  #pragma unroll
  for (int e = 0; e < 4; ++e) { int i = t + (e << 6); op[i] = s[i]; }
}

__device__ __forceinline__ int radial_bin(int r2) {
  int j = (int)(sqrtf((float)r2) * 0.25f);
  while ((j + 1) * (j + 1) * 16 <= r2) ++j;
  while (j > 0 && j * j * 16 > r2) --j;
  return j;
}

__global__ __launch_bounds__(64)
void fft_cols_radial(const float2* __restrict__ f, float* __restrict__ radial) {
  __shared__ float2 s[256];
  __shared__ float2 tw[128];
  __shared__ float bins[32];
  int b = blockIdx.x >> 8;
  int col = blockIdx.x & 255;
  int t = threadIdx.x;
  fill_tw(tw, t);
  const float2* base = f + (size_t)b * 65536 + col;
  #pragma unroll
  for (int e = 0; e < 4; ++e) {
    int i = t + (e << 6);
    s[bitrev8(i)] = base[(size_t)i * 256];
  }
  if (t < 32) bins[t] = 0.f;
  __syncthreads();
  fft256(s, tw, t);
  #pragma unroll
  for (int e = 0; e < 4; ++e) {
    int i = t + (e << 6);
    float2 v = s[i];
    float ps = v.x * v.x + v.y * v.y;
    int dy = i - 128, dx = col - 128;
    int r2 = dx * dx + dy * dy;
    if (r2 < 16384) atomicAdd(&bins[radial_bin(r2)], ps);
  }
  __syncthreads();
  if (t < 32) atomicAdd(&radial[b * 32 + t], bins[t]);
}

__global__ __launch_bounds__(256)
void radial_finalize(const float* __restrict__ radial, float* __restrict__ pf0) {
  __shared__ int cnt[32];
  int b = blockIdx.x, t = threadIdx.x;
  if (t < 32) cnt[t] = 0;
  __syncthreads();
  int dy = t - 128;
  for (int k = 0; k < 256; ++k) {
    int dx = k - 128;
    int r2 = dx * dx + dy * dy;
    if (r2 < 16384) atomicAdd(&cnt[radial_bin(r2)], 1);
  }
  __syncthreads();
  if (t < 32) {
    float c = (float)cnt[t];
    float sum = radial[b * 32 + t];
    float val = c > 0.f ? sum / fmaxf(c, 1.f) : 0.f;
    pf0[b * 32 + t] = logf(val + 1e-10f);
  }
}

// ---------------- weight transform: OIHW fp32 -> [tap][co][ci] f16 ----------

__global__ __launch_bounds__(256)
void wtrans(const float* __restrict__ w, _Float16* __restrict__ out,
            int COUT, int CIN, int KK, int co_off) {
  int i = blockIdx.x * 256 + threadIdx.x;
  int total = COUT * CIN * KK;
  if (i >= total) return;
  int ci = i % CIN;
  int r = i / CIN;
  int co = r % COUT;
  int tap = r / COUT;
  out[i] = (_Float16)w[((size_t)(co_off + co) * CIN + ci) * KK + tap];
}

// ---------------- conv1 (Cin=1, 5x5) ----------------------------------------
// stats: block = 8 output rows x one image; LDS-staged input; per-thread
// channel (t&31) x column-group (t>>5); block-reduce -> 64 atomics/block.

__global__ __launch_bounds__(256)
void conv1_stats_v2(const float* __restrict__ x, const float* __restrict__ w,
                    float* __restrict__ stats) {
  __shared__ float lds[12 * 260];
  __shared__ float r1[4][32], r2[4][32];
  int t = threadIdx.x;
  int y0 = blockIdx.x * 8, n = blockIdx.y;
  const float* xp = x + (size_t)n * 65536;
  for (int i = t; i < 12 * 260; i += 256) {
    int r = i / 260, xx = i % 260;
    int gy = y0 + r - 2, gx = xx - 2;
    lds[i] = (gy >= 0 && gy < 256 && gx >= 0 && gx < 256) ? xp[gy * 256 + gx] : 0.f;
  }
  __syncthreads();
  int c = t & 31, xg = t >> 5;
  float wreg[25];
  #pragma unroll
  for (int k = 0; k < 25; ++k) wreg[k] = w[c * 25 + k];
  float s1 = 0.f, s2 = 0.f;
  for (int r = 0; r < 8; ++r) {
    for (int px = xg; px < 256; px += 8) {
      float acc = 0.f;
      #pragma unroll
      for (int ky = 0; ky < 5; ++ky)
        #pragma unroll
        for (int kx = 0; kx < 5; ++kx)
          acc += wreg[ky * 5 + kx] * lds[(r + ky) * 260 + px + kx];
      s1 += acc; s2 += acc * acc;
    }
  }
  s1 += __shfl_down(s1, 32);
  s2 += __shfl_down(s2, 32);
  if ((t & 63) < 32) { r1[t >> 6][t & 31] = s1; r2[t >> 6][t & 31] = s2; }
  __syncthreads();
  if (t < 32) {
    atomicAdd(&stats[t],      r1[0][t] + r1[1][t] + r1[2][t] + r1[3][t]);
    atomicAdd(&stats[32 + t], r2[0][t] + r2[1][t] + r2[2][t] + r2[3][t]);
  }
}

// apply: BN+ReLU+2x2 maxpool fused, writes pool1 NHWC f16 [16][128][128][32]
__global__ __launch_bounds__(256)
void conv1_apply_v2(const float* __restrict__ x, const float* __restrict__ w,
                    const float* __restrict__ stats, const float* __restrict__ g,
                    const float* __restrict__ bb, _Float16* __restrict__ pool1) {
  __shared__ float lds[6 * 260];
  int t = threadIdx.x;
  int py = blockIdx.x, n = blockIdx.y;
  const float* xp = x + (size_t)n * 65536;
  for (int i = t; i < 6 * 260; i += 256) {
    int r = i / 260, xx = i % 260;
    int gy = 2 * py + r - 2, gx = xx - 2;
    lds[i] = (gy >= 0 && gy < 256 && gx >= 0 && gx < 256) ? xp[gy * 256 + gx] : 0.f;
  }
  __syncthreads();
  int c = t & 31, pxg = t >> 5;
  float wreg[25];
  #pragma unroll
  for (int k = 0; k < 25; ++k) wreg[k] = w[c * 25 + k];
  float mean = stats[c] * (1.f / 1048576.f);
  float var  = stats[32 + c] * (1.f / 1048576.f) - mean * mean;
  float sc = g[c] / sqrtf(var + 1e-5f);
  float sh = bb[c] - mean * sc;
  for (int px = pxg; px < 128; px += 8) {
    float best = -1e30f;
    #pragma unroll
    for (int sy = 0; sy < 2; ++sy) {
      #pragma unroll
      for (int sx = 0; sx < 2; ++sx) {
        float acc = 0.f;
        #pragma unroll
        for (int ky = 0; ky < 5; ++ky)
          #pragma unroll
          for (int kx = 0; kx < 5; ++kx)
            acc += wreg[ky * 5 + kx] * lds[(sy + ky) * 260 + 2 * px + sx + kx];
        best = fmaxf(best, acc * sc + sh);
      }
    }
    pool1[(((size_t)n * 128 + py) * 128 + px) * 32 + c] = (_Float16)fmaxf(best, 0.f);
  }
}

// ---------------- implicit-GEMM MFMA conv -----------------------------------
// in: NHWC f16 [N,H,W,CIN]; wb: [tap][co][ci] f16; out: NHWC fp32 [N,H,W,COUT]
// Block tile: (32*COT) co x 64 positions. 4 waves 2x2. LDS input tile with
// halo; ci-chunk stride padded to 40 halfwords (bank-conflict-free b128).

template <int CIN, int COUT, int H, int W, int K, int TW, int COT>
__global__ __launch_bounds__(256)
void conv_mfma(const _Float16* __restrict__ in, const _Float16* __restrict__ wb,
               float* __restrict__ out) {
  constexpr int P = K / 2, TH = 64 / TW, R = TH + 2 * P, XW = TW + 2 * P;
  constexpr int TAPS = K * K, NCC = CIN / 32, CS = 40;
  __shared__ _Float16 lds[R * XW * CS];
  int t = threadIdx.x;
  int lane = t & 63, wv = t >> 6;
  int lane15 = lane & 15, quad = lane >> 4;
  constexpr int WT = W / TW;
  int x0 = (blockIdx.x % WT) * TW, y0 = (blockIdx.x / WT) * TH;
  int coB = blockIdx.y * (32 * COT);
  int nb = blockIdx.z;
  int co_off = (wv & 1) * (16 * COT);
  int pos_off = (wv >> 1) * 32;

  f32x4 acc[COT][2];
  #pragma unroll
  for (int ct = 0; ct < COT; ++ct)
    #pragma unroll
    for (int pt = 0; pt < 2; ++pt)
      #pragma unroll
      for (int e = 0; e < 4; ++e) acc[ct][pt][e] = 0.f;

  int bbase[2];
  #pragma unroll
  for (int pt = 0; pt < 2; ++pt) {
    int n = pos_off + pt * 16 + lane15;
    int ly = n / TW, lx = n % TW;
    bbase[pt] = (ly * XW + lx) * CS + quad * 8;
  }
  const _Float16* aptr[COT];
  #pragma unroll
  for (int ct = 0; ct < COT; ++ct)
    aptr[ct] = wb + (coB + co_off + ct * 16 + lane15) * CIN + quad * 8;

  const _Float16* inb = in + (size_t)nb * H * W * CIN;

  for (int cc = 0; cc < NCC; ++cc) {
    constexpr int ITEMS = R * XW * 4;
    for (int i = t; i < ITEMS; i += 256) {
      int sub = i & 3, pix = i >> 2;
      int r = pix / XW, xx = pix % XW;
      int gy = y0 + r - P, gx = x0 + xx - P;
      half8 v;
      #pragma unroll
      for (int j = 0; j < 8; ++j) v[j] = (_Float16)0.f;
      if (gy >= 0 && gy < H && gx >= 0 && gx < W)
        v = *(const half8*)(inb + (gy * W + gx) * CIN + cc * 32 + sub * 8);
      *(half8*)(&lds[pix * CS + sub * 8]) = v;
    }
    __syncthreads();
    #pragma unroll
    for (int tap = 0; tap < TAPS; ++tap) {
      constexpr int stride_tap = 0;  // (silence unused warnings pattern)
      (void)stride_tap;
      int ky = tap / K, kx = tap % K;
      half8 a[COT], b[2];
      #pragma unroll
      for (int ct = 0; ct < COT; ++ct)
        a[ct] = *(const half8*)(aptr[ct] + (size_t)tap * COUT * CIN + cc * 32);
      #pragma unroll
      for (int pt = 0; pt < 2; ++pt)
        b[pt] = *(const half8*)(&lds[bbase[pt] + (ky * XW + kx) * CS]);
      #pragma unroll
      for (int ct = 0; ct < COT; ++ct)
        #pragma unroll
        for (int pt = 0; pt < 2; ++pt)
          acc[ct][pt] = __builtin_amdgcn_mfma_f32_16x16x32_f16(
              a[ct], b[pt], acc[ct][pt], 0, 0, 0);
    }
    __syncthreads();
  }

  #pragma unroll
  for (int ct = 0; ct < COT; ++ct)
    #pragma unroll
    for (int pt = 0; pt < 2; ++pt) {
      int co = coB + co_off + ct * 16 + quad * 4;
      int n = pos_off + pt * 16 + lane15;
      int y = y0 + n / TW, x = x0 + n % TW;
      float* op = out + (((size_t)nb * H + y) * W + x) * COUT + co;
      *(f32x4*)op = acc[ct][pt];
    }
}

// ---------------- BN over NHWC fp32 -----------------------------------------

__global__ __launch_bounds__(256)
void bn_stats_nhwc(const float* __restrict__ x, float* __restrict__ stats,
                   int C, int HW) {
  __shared__ float r1[4][32], r2[4][32];
  int t = threadIdx.x;
  int cg = blockIdx.x, n = blockIdx.y, pz = blockIdx.z, PZ = gridDim.z;
  int c = cg * 32 + (t & 31);
  int pl = t >> 5;
  int chunk = HW / PZ;
  float s1 = 0.f, s2 = 0.f;
  for (int p = pz * chunk + pl; p < (pz + 1) * chunk; p += 8) {
    float v = x[((size_t)n * HW + p) * C + c];
    s1 += v; s2 += v * v;
  }
  s1 += __shfl_down(s1, 32);
  s2 += __shfl_down(s2, 32);
  if ((t & 63) < 32) { r1[t >> 6][t & 31] = s1; r2[t >> 6][t & 31] = s2; }
  __syncthreads();
  if (t < 32) {
    atomicAdd(&stats[cg * 32 + t],     r1[0][t] + r1[1][t] + r1[2][t] + r1[3][t]);
    atomicAdd(&stats[C + cg * 32 + t], r2[0][t] + r2[1][t] + r2[2][t] + r2[3][t]);
  }
}

// BN+ReLU+2x2 maxpool: fp32 NHWC [N,H,W,C] -> f16 NHWC [N,H/2,W/2,Cstr] @c_off
__global__ __launch_bounds__(256)
void bn_pool_nhwc(const float* __restrict__ x, const float* __restrict__ stats,
                  const float* __restrict__ g, const float* __restrict__ bb,
                  _Float16* __restrict__ out, int C, int H, int W,
                  int c_off, int Cstr, float invN) {
  __shared__ float scs[256], shs[256];
  int t = threadIdx.x;
  int py = blockIdx.x, n = blockIdx.y;
  for (int c = t; c < C; c += 256) {
    float mean = stats[c] * invN;
    float var  = stats[C + c] * invN - mean * mean;
    float sc = g[c] / sqrtf(var + 1e-5f);
    scs[c] = sc; shs[c] = bb[c] - mean * sc;
  }
  __syncthreads();
  int W2 = W >> 1;
  int tot = W2 * C;
  for (int i = t; i < tot; i += 256) {
    int c = i % C, px = i / C;
    const float* p0 = x + (((size_t)n * H + 2 * py) * W + 2 * px) * C + c;
    float sc = scs[c], sh = shs[c];
    float a = fmaxf(p0[0] * sc + sh, 0.f);
    float b = fmaxf(p0[C] * sc + sh, 0.f);
    float d = fmaxf(p0[(size_t)W * C] * sc + sh, 0.f);
    float e = fmaxf(p0[(size_t)W * C + C] * sc + sh, 0.f);
    out[(((size_t)n * (H / 2) + py) * W2 + px) * Cstr + c_off + c] =
        (_Float16)fmaxf(fmaxf(a, b), fmaxf(d, e));
  }
}

// BN+ReLU elementwise: fp32 NHWC -> f16 NHWC (conv4 path, no pool)
__global__ __launch_bounds__(256)
void bn_relu_f16_nhwc(const float* __restrict__ x, const float* __restrict__ stats,
                      const float* __restrict__ g, const float* __restrict__ bb,
                      _Float16* __restrict__ out, int C, int HW, float invN) {
  __shared__ float scs[256], shs[256];
  int t = threadIdx.x;
  int n = blockIdx.y;
  for (int c = t; c < C; c += 256) {
    float mean = stats[c] * invN;
    float var  = stats[C + c] * invN - mean * mean;
    float sc = g[c] / sqrtf(var + 1e-5f);
    scs[c] = sc; shs[c] = bb[c] - mean * sc;
  }
  __syncthreads();
  int total = HW * C;
  int chunk = total / gridDim.x;
  int base = blockIdx.x * chunk;
  const float* xp = x + (size_t)n * total;
  _Float16* op = out + (size_t)n * total;
  for (int i = base + t; i < base + chunk; i += 256) {
    int c = i % C;
    op[i] = (_Float16)fmaxf(xp[i] * scs[c] + shs[c], 0.f);
  }
}

// pconv epilogue: BN+ReLU+8x8 avgpool -> concat[n][c*16+opix] (fp32)
__global__ __launch_bounds__(256)
void bn_avgpool_concat(const float* __restrict__ x, const float* __restrict__ stats,
                       const float* __restrict__ g, const float* __restrict__ bb,
                       float* __restrict__ concat, float invN) {
  __shared__ float scs[128], shs[128];
  int t = threadIdx.x;
  int n = blockIdx.x;
  for (int c = t; c < 128; c += 256) {
    float mean = stats[c] * invN;
    float var  = stats[128 + c] * invN - mean * mean;
    float sc = g[c] / sqrtf(var + 1e-5f);
    scs[c] = sc; shs[c] = bb[c] - mean * sc;
  }
  __syncthreads();
  for (int i = t; i < 2048; i += 256) {
    int c = i & 127, opix = i >> 7;
    int py = opix >> 2, px = opix & 3;
    float sc = scs[c], sh = shs[c];
    float s = 0.f;
    for (int yy = 0; yy < 8; ++yy)
      for (int xx = 0; xx < 8; ++xx)
        s += fmaxf(x[(((size_t)n * 32 + py * 8 + yy) * 32 + px * 8 + xx) * 128 + c] * sc + sh, 0.f);
    concat[(size_t)n * 2112 + c * 16 + opix] = s * (1.f / 64.f);
  }
}

// ---------------- linear (one wave per output element) ----------------------

__global__ __launch_bounds__(64)
void linear_k(const float* __restrict__ in, const float* __restrict__ w,
              const float* __restrict__ bias, float* __restrict__ out,
              int I, int in_stride, int out_stride, int relu) {
  int o = blockIdx.x, b = blockIdx.y;
  int lane = threadIdx.x;
  const float* ip = in + (size_t)b * in_stride;
  const float* wp = w + (size_t)o * I;
  float acc = 0.f;
  for (int i = lane; i < I; i += 64) acc += ip[i] * wp[i];
  #pragma unroll
  for (int off = 32; off > 0; off >>= 1) acc += __shfl_down(acc, off);
  if (lane == 0) {
    float v = acc + bias[o];
    if (relu) v = fmaxf(v, 0.f);
    out[(size_t)b * out_stride + o] = v;
  }
}

// ---------------------------------------------------------------------------

extern "C" void kernel_launch(void* const* d_in, const int* in_sizes, int n_in,
                              void* d_out, int out_size, void* d_ws, size_t ws_size,
                              hipStream_t stream) {
  (void)in_sizes; (void)n_in; (void)out_size; (void)ws_size;
  const float* x   = (const float*)d_in[0];
  const float* cw1 = (const float*)d_in[1];
  const float* g1  = (const float*)d_in[3];
  const float* bb1 = (const float*)d_in[4];
  const float* cw2 = (const float*)d_in[5];
  const float* g2  = (const float*)d_in[7];
  const float* bb2 = (const float*)d_in[8];
  const float* cw3 = (const float*)d_in[9];
  const float* g3  = (const float*)d_in[11];
  const float* bb3 = (const float*)d_in[12];
  const float* cw4 = (const float*)d_in[13];
  const float* g4  = (const float*)d_in[15];
  const float* bb4 = (const float*)d_in[16];
  const float* pcw = (const float*)d_in[17];
  const float* pg  = (const float*)d_in[19];
  const float* pbb = (const float*)d_in[20];
  const float* pw1 = (const float*)d_in[21];
  const float* pb1 = (const float*)d_in[22];
  const float* pw2 = (const float*)d_in[23];
  const float* pb2 = (const float*)d_in[24];
  const float* pw3 = (const float*)d_in[25];
  const float* pb3 = (const float*)d_in[26];
  const float* fw1 = (const float*)d_in[27];
  const float* fb1 = (const float*)d_in[28];
  const float* fw2 = (const float*)d_in[29];
  const float* fb2 = (const float*)d_in[30];
  const float* fw3 = (const float*)d_in[31];
  const float* fb3 = (const float*)d_in[32];
  const float* fw4 = (const float*)d_in[33];
  const float* fb4 = (const float*)d_in[34];

  char* base = (char*)d_ws;
  // B region (33.55 MB): fftbuf -> conv2out half -> conv3out -> conv4out+act4+pconvout
  float*     Bf      = (float*)(base + 0);
  float2*    fftbuf  = (float2*)(base + 0);
  float*     conv2o  = (float*)(base + 0);             // [16,128,128,32] fp32
  float*     conv3o  = (float*)(base + 0);             // [16,64,64,128] fp32
  float*     conv4o  = (float*)(base + 0);             // [16,32,32,256] fp32
  _Float16*  act4    = (_Float16*)(base + 16777216);   // [16,32,32,256] f16
  float*     pconvo  = (float*)(base + 25165824);      // [16,32,32,128] fp32
  (void)Bf;
  _Float16*  pool1   = (_Float16*)(base + 33554432);   // [16,128,128,32] f16
  _Float16*  pool2   = (_Float16*)(base + 50331648);   // [16,64,64,64]  f16
  _Float16*  pool3   = (_Float16*)(base + 58720256);   // [16,32,32,128] f16
  _Float16*  wb2a    = (_Float16*)(base + 62914560);   // 25*32*32
  _Float16*  wb2b    = (_Float16*)(base + 62965760);
  _Float16*  wb3     = (_Float16*)(base + 63016960);   // 9*128*64
  _Float16*  wb4     = (_Float16*)(base + 63164416);   // 9*256*128
  _Float16*  wbp     = (_Float16*)(base + 63754240);   // 9*128*256
  float*     zbase   = (float*)(base + 64344064);      // 1728 floats
  float*     stats1  = zbase;            // 64
  float*     stats2  = zbase + 64;       // 128 (2 halves of 64)
  float*     stats3  = zbase + 192;      // 256
  float*     stats4  = zbase + 448;      // 512
  float*     stats5  = zbase + 960;      // 256
  float*     radial  = zbase + 1216;     // 512
  float*     pf0     = (float*)(base + 64350976);
  float*     pf1     = (float*)(base + 64353024);
  float*     pf2     = (float*)(base + 64369408);
  float*     concat  = (float*)(base + 64377600);      // 16*2112
  float*     fc1o    = (float*)(base + 64512768);
  float*     fc2o    = (float*)(base + 64545536);
  float*     fc3o    = (float*)(base + 64561920);

  hipMemsetAsync(zbase, 0, 1728 * sizeof(float), stream);

  // weight transforms (every call; ws is re-poisoned)
  wtrans<<<100,  256, 0, stream>>>(cw2, wb2a, 32, 32, 25, 0);
  wtrans<<<100,  256, 0, stream>>>(cw2, wb2b, 32, 32, 25, 32);
  wtrans<<<288,  256, 0, stream>>>(cw3, wb3, 128, 64, 9, 0);
  wtrans<<<1152, 256, 0, stream>>>(cw4, wb4, 256, 128, 9, 0);
  wtrans<<<1152, 256, 0, stream>>>(pcw, wbp, 128, 256, 9, 0);

  // ---- FFT / power-features branch (fftbuf aliases B; done before conv2) ----
  fft_rows<<<4096, 64, 0, stream>>>(x, fftbuf);
  fft_cols_radial<<<4096, 64, 0, stream>>>(fftbuf, radial);
  radial_finalize<<<16, 256, 0, stream>>>(radial, pf0);
  linear_k<<<dim3(256, 16), 64, 0, stream>>>(pf0, pw1, pb1, pf1, 32, 32, 256, 1);
  linear_k<<<dim3(128, 16), 64, 0, stream>>>(pf1, pw2, pb2, pf2, 256, 256, 128, 1);
  linear_k<<<dim3(64, 16), 64, 0, stream>>>(pf2, pw3, pb3, concat + 2048, 128, 128, 2112, 1);

  // ---- conv1 ----
  conv1_stats_v2<<<dim3(32, 16), 256, 0, stream>>>(x, cw1, stats1);
  conv1_apply_v2<<<dim3(128, 16), 256, 0, stream>>>(x, cw1, stats1, g1, bb1, pool1);

  // ---- conv2 (two Cout halves; BN is per-channel so this is exact) ----
  conv_mfma<32, 32, 128, 128, 5, 64, 1><<<dim3(256, 1, 16), 256, 0, stream>>>(
      pool1, wb2a, conv2o);
  bn_stats_nhwc<<<dim3(1, 16, 8), 256, 0, stream>>>(conv2o, stats2, 32, 16384);
  bn_pool_nhwc<<<dim3(64, 16), 256, 0, stream>>>(
      conv2o, stats2, g2, bb2, pool2, 32, 128, 128, 0, 64, 1.f / 262144.f);
  conv_mfma<32, 32, 128, 128, 5, 64, 1><<<dim3(256, 1, 16), 256, 0, stream>>>(
      pool1, wb2b, conv2o);
  bn_stats_nhwc<<<dim3(1, 16, 8), 256, 0, stream>>>(conv2o, stats2 + 64, 32, 16384);
  bn_pool_nhwc<<<dim3(64, 16), 256, 0, stream>>>(
      conv2o, stats2 + 64, g2 + 32, bb2 + 32, pool2, 32, 128, 128, 32, 64, 1.f / 262144.f);

  // ---- conv3 ----
  conv_mfma<64, 128, 64, 64, 3, 64, 2><<<dim3(64, 2, 16), 256, 0, stream>>>(
      pool2, wb3, conv3o);
  bn_stats_nhwc<<<dim3(4, 16, 8), 256, 0, stream>>>(conv3o, stats3, 128, 4096);
  bn_pool_nhwc<<<dim3(32, 16), 256, 0, stream>>>(
      conv3o, stats3, g3, bb3, pool3, 128, 64, 64, 0, 128, 1.f / 65536.f);

  // ---- conv4 ----
  conv_mfma<128, 256, 32, 32, 3, 32, 2><<<dim3(16, 4, 16), 256, 0, stream>>>(
      pool3, wb4, conv4o);
  bn_stats_nhwc<<<dim3(8, 16, 8), 256, 0, stream>>>(conv4o, stats4, 256, 1024);
  bn_relu_f16_nhwc<<<dim3(8, 16), 256, 0, stream>>>(
      conv4o, stats4, g4, bb4, act4, 256, 1024, 1.f / 16384.f);

  // ---- pconv ----
  conv_mfma<256, 128, 32, 32, 3, 32, 2><<<dim3(16, 2, 16), 256, 0, stream>>>(
      act4, wbp, pconvo);
  bn_stats_nhwc<<<dim3(4, 16, 8), 256, 0, stream>>>(pconvo, stats5, 128, 1024);
  bn_avgpool_concat<<<16, 256, 0, stream>>>(pconvo, stats5, pg, pbb, concat, 1.f / 16384.f);

  // ---- classifier head ----
  linear_k<<<dim3(512, 16), 64, 0, stream>>>(concat, fw1, fb1, fc1o, 2112, 2112, 512, 1);
  linear_k<<<dim3(256, 16), 64, 0, stream>>>(fc1o, fw2, fb2, fc2o, 512, 512, 256, 1);
  linear_k<<<dim3(128, 16), 64, 0, stream>>>(fc2o, fw3, fb3, fc3o, 256, 256, 128, 1);
  linear_k<<<dim3(2, 16), 64, 0, stream>>>(fc3o, fw4, fb4, (float*)d_out, 128, 128, 2, 0);
}

// Round 3
// 713.396 us; speedup vs baseline: 5.8085x; 1.2033x over previous
//
#include <hip/hip_runtime.h>
#include <math.h>

// ---------------------------------------------------------------------------
// R3: convs 2-5 implicit-GEMM MFMA (f16 in/out, fp32 accum), 2D spatial tiles.
// Radial bin counts computed analytically (no atomics). Column FFT coalesced
// (8 cols/block). Conv biases dropped (training-mode BN absorbs them).
// MFMA 16x16x32 f16: A m=lane&15,k=quad*8+j; B n=lane&15,k=quad*8+j;
//                    D col(n)=lane&15, row(m)=quad*4+reg.
// ---------------------------------------------------------------------------

#define PI2F 6.283185307179586f

typedef _Float16 half8 __attribute__((ext_vector_type(8)));
typedef _Float16 half4v __attribute__((ext_vector_type(4)));
typedef float f32x4 __attribute__((ext_vector_type(4)));

// ---------------- FFT branch ------------------------------------------------

__device__ __forceinline__ int bitrev8(int x) {
  x = ((x & 0x0F) << 4) | ((x >> 4) & 0x0F);
  x = ((x & 0x33) << 2) | ((x >> 2) & 0x33);
  x = ((x & 0x55) << 1) | ((x >> 1) & 0x55);
  return x;
}

__global__ __launch_bounds__(64)
void fft_rows(const float* __restrict__ x, float2* __restrict__ out) {
  __shared__ float2 s[256];
  __shared__ float2 tw[128];
  int blk = blockIdx.x;
  const float* rowp = x + (size_t)blk * 256;
  int t = threadIdx.x;
  for (int i = t; i < 128; i += 64) {
    float sn, cs;
    sincosf(-(PI2F / 256.f) * (float)i, &sn, &cs);
    tw[i] = make_float2(cs, sn);
  }
  #pragma unroll
  for (int e = 0; e < 4; ++e) {
    int i = t + (e << 6);
    s[bitrev8(i)] = make_float2(rowp[i], 0.f);
  }
  __syncthreads();
  #pragma unroll
  for (int st = 1; st <= 8; ++st) {
    int half = 1 << (st - 1);
    #pragma unroll
    for (int j = 0; j < 2; ++j) {
      int bf = t + (j << 6);
      int pos = bf & (half - 1);
      int grp = bf >> (st - 1);
      int i0 = (grp << st) | pos;
      int i1 = i0 + half;
      int k = pos << (8 - st);
      float cs = tw[k].x, sn = tw[k].y;
      float2 a = s[i0], b = s[i1];
      float tr = cs * b.x - sn * b.y;
      float ti = cs * b.y + sn * b.x;
      s[i0] = make_float2(a.x + tr, a.y + ti);
      s[i1] = make_float2(a.x - tr, a.y - ti);
    }
    __syncthreads();
  }
  float2* op = out + (size_t)blk * 256;
  #pragma unroll
  for (int e = 0; e < 4; ++e) { int i = t + (e << 6); op[i] = s[i]; }
}

__device__ __forceinline__ int radial_bin(int r2) {
  int j = (int)(sqrtf((float)r2) * 0.25f);
  while ((j + 1) * (j + 1) * 16 <= r2) ++j;
  while (j > 0 && j * j * 16 > r2) --j;
  return j;
}

// 8 columns per block, 256 threads; coalesced loads; 32 threads per col FFT.
__global__ __launch_bounds__(256)
void fft_cols_radial_v2(const float2* __restrict__ f, float* __restrict__ radial) {
  __shared__ float2 s[8][258];
  __shared__ float2 tw[128];
  __shared__ float bins[8][32];
  int b = blockIdx.x >> 5;
  int col0 = (blockIdx.x & 31) * 8;
  int t = threadIdx.x;
  for (int i = t; i < 128; i += 256) {
    float sn, cs;
    sincosf(-(PI2F / 256.f) * (float)i, &sn, &cs);
    tw[i] = make_float2(cs, sn);
  }
  ((float*)bins)[t] = 0.f;
  for (int idx = t; idx < 2048; idx += 256) {
    int row = idx >> 3, c = idx & 7;
    s[c][bitrev8(row)] = f[(size_t)b * 65536 + row * 256 + col0 + c];
  }
  __syncthreads();
  int c = t >> 5, l = t & 31;
  float2* sc = &s[c][0];
  #pragma unroll
  for (int st = 1; st <= 8; ++st) {
    int half = 1 << (st - 1);
    #pragma unroll
    for (int j = 0; j < 4; ++j) {
      int bf = l + (j << 5);
      int pos = bf & (half - 1);
      int grp = bf >> (st - 1);
      int i0 = (grp << st) | pos;
      int i1 = i0 + half;
      int k = pos << (8 - st);
      float cs = tw[k].x, sn = tw[k].y;
      float2 a = sc[i0], bb = sc[i1];
      float tr = cs * bb.x - sn * bb.y;
      float ti = cs * bb.y + sn * bb.x;
      sc[i0] = make_float2(a.x + tr, a.y + ti);
      sc[i1] = make_float2(a.x - tr, a.y - ti);
    }
    __syncthreads();
  }
  int dx = col0 + c - 128;
  #pragma unroll
  for (int e = 0; e < 8; ++e) {
    int i = l * 8 + e;
    float2 v = sc[i];
    float ps = v.x * v.x + v.y * v.y;
    int dy = i - 128;
    int r2 = dx * dx + dy * dy;
    if (r2 < 16384) atomicAdd(&bins[c][radial_bin(r2)], ps);
  }
  __syncthreads();
  if (t < 32) {
    float s0 = bins[0][t] + bins[1][t] + bins[2][t] + bins[3][t] +
               bins[4][t] + bins[5][t] + bins[6][t] + bins[7][t];
    atomicAdd(&radial[b * 32 + t], s0);
  }
}

__device__ __forceinline__ int isqrt_(int v) {
  int r = (int)sqrtf((float)v);
  while (r * r > v) --r;
  while ((r + 1) * (r + 1) <= v) ++r;
  return r;
}

// analytic bin counts: no atomics, 32 threads x 256 rows
__global__ __launch_bounds__(64)
void radial_finalize_v2(const float* __restrict__ radial, float* __restrict__ pf0) {
  int b = blockIdx.x, t = threadIdx.x;
  if (t >= 32) return;
  int lo = 16 * t * t, hi = 16 * (t + 1) * (t + 1);
  int cnt = 0;
  for (int dy = -128; dy <= 127; ++dy) {
    int d2 = dy * dy;
    int tHi = hi - 1 - d2;
    if (tHi < 0) continue;
    int rHi = isqrt_(tHi);
    int nHi = min(rHi, 127) + min(rHi, 128) + 1;
    int nLo = 0;
    int tLo = lo - 1 - d2;
    if (tLo >= 0) { int rLo = isqrt_(tLo); nLo = min(rLo, 127) + min(rLo, 128) + 1; }
    cnt += nHi - nLo;
  }
  float cf = (float)cnt;
  float sum = radial[b * 32 + t];
  float val = cf > 0.f ? sum / fmaxf(cf, 1.f) : 0.f;
  pf0[b * 32 + t] = logf(val + 1e-10f);
}

// ---------------- weight transform: OIHW fp32 -> [tap][co][ci] f16 ----------

__global__ __launch_bounds__(256)
void wtrans(const float* __restrict__ w, _Float16* __restrict__ out,
            int COUT, int CIN, int KK) {
  int i = blockIdx.x * 256 + threadIdx.x;
  int total = COUT * CIN * KK;
  if (i >= total) return;
  int ci = i % CIN;
  int r = i / CIN;
  int co = r % COUT;
  int tap = r / COUT;
  out[i] = (_Float16)w[((size_t)co * CIN + ci) * KK + tap];
}

// ---------------- conv1 (Cin=1, 5x5) ----------------------------------------

__global__ __launch_bounds__(256)
void conv1_stats_v2(const float* __restrict__ x, const float* __restrict__ w,
                    float* __restrict__ stats) {
  __shared__ float lds[12 * 260];
  __shared__ float r1[4][32], r2[4][32];
  int t = threadIdx.x;
  int y0 = blockIdx.x * 8, n = blockIdx.y;
  const float* xp = x + (size_t)n * 65536;
  for (int i = t; i < 12 * 260; i += 256) {
    int r = i / 260, xx = i % 260;
    int gy = y0 + r - 2, gx = xx - 2;
    lds[i] = (gy >= 0 && gy < 256 && gx >= 0 && gx < 256) ? xp[gy * 256 + gx] : 0.f;
  }
  __syncthreads();
  int c = t & 31, xg = t >> 5;
  float wreg[25];
  #pragma unroll
  for (int k = 0; k < 25; ++k) wreg[k] = w[c * 25 + k];
  float s1 = 0.f, s2 = 0.f;
  for (int r = 0; r < 8; ++r) {
    for (int px = xg; px < 256; px += 8) {
      float acc = 0.f;
      #pragma unroll
      for (int ky = 0; ky < 5; ++ky)
        #pragma unroll
        for (int kx = 0; kx < 5; ++kx)
          acc += wreg[ky * 5 + kx] * lds[(r + ky) * 260 + px + kx];
      s1 += acc; s2 += acc * acc;
    }
  }
  s1 += __shfl_down(s1, 32);
  s2 += __shfl_down(s2, 32);
  if ((t & 63) < 32) { r1[t >> 6][t & 31] = s1; r2[t >> 6][t & 31] = s2; }
  __syncthreads();
  if (t < 32) {
    atomicAdd(&stats[t],      r1[0][t] + r1[1][t] + r1[2][t] + r1[3][t]);
    atomicAdd(&stats[32 + t], r2[0][t] + r2[1][t] + r2[2][t] + r2[3][t]);
  }
}

__global__ __launch_bounds__(256)
void conv1_apply_v2(const float* __restrict__ x, const float* __restrict__ w,
                    const float* __restrict__ stats, const float* __restrict__ g,
                    const float* __restrict__ bb, _Float16* __restrict__ pool1) {
  __shared__ float lds[6 * 260];
  int t = threadIdx.x;
  int py = blockIdx.x, n = blockIdx.y;
  const float* xp = x + (size_t)n * 65536;
  for (int i = t; i < 6 * 260; i += 256) {
    int r = i / 260, xx = i % 260;
    int gy = 2 * py + r - 2, gx = xx - 2;
    lds[i] = (gy >= 0 && gy < 256 && gx >= 0 && gx < 256) ? xp[gy * 256 + gx] : 0.f;
  }
  __syncthreads();
  int c = t & 31, pxg = t >> 5;
  float wreg[25];
  #pragma unroll
  for (int k = 0; k < 25; ++k) wreg[k] = w[c * 25 + k];
  float mean = stats[c] * (1.f / 1048576.f);
  float var  = stats[32 + c] * (1.f / 1048576.f) - mean * mean;
  float sc = g[c] / sqrtf(var + 1e-5f);
  float sh = bb[c] - mean * sc;
  for (int px = pxg; px < 128; px += 8) {
    float best = -1e30f;
    #pragma unroll
    for (int sy = 0; sy < 2; ++sy) {
      #pragma unroll
      for (int sx = 0; sx < 2; ++sx) {
        float acc = 0.f;
        #pragma unroll
        for (int ky = 0; ky < 5; ++ky)
          #pragma unroll
          for (int kx = 0; kx < 5; ++kx)
            acc += wreg[ky * 5 + kx] * lds[(sy + ky) * 260 + 2 * px + sx + kx];
        best = fmaxf(best, acc * sc + sh);
      }
    }
    pool1[(((size_t)n * 128 + py) * 128 + px) * 32 + c] = (_Float16)fmaxf(best, 0.f);
  }
}

// ---------------- implicit-GEMM MFMA conv (2D tile, f16 out) ----------------
// Block = 4 waves: 2 (co) x 2 (pos). M=32*COT, N=32*PT = TH*TW positions.

template <int CIN, int COUT, int H, int W, int K, int TH, int TW, int COT, int PT>
__global__ __launch_bounds__(256)
void conv_mfma(const _Float16* __restrict__ in, const _Float16* __restrict__ wb,
               _Float16* __restrict__ out) {
  constexpr int P = K / 2, R = TH + 2 * P, XW = TW + 2 * P;
  constexpr int TAPS = K * K, NCC = CIN / 32, CS = 40;
  static_assert(TH * TW == 32 * PT, "pos tile mismatch");
  __shared__ _Float16 lds[R * XW * CS];
  int t = threadIdx.x;
  int lane = t & 63, wv = t >> 6;
  int lane15 = lane & 15, quad = lane >> 4;
  constexpr int WT = W / TW;
  int x0 = (blockIdx.x % WT) * TW, y0 = (blockIdx.x / WT) * TH;
  int coB = blockIdx.y * (32 * COT);
  int nb = blockIdx.z;
  int co_off = (wv & 1) * (16 * COT);
  int pos_off = (wv >> 1) * (16 * PT);

  f32x4 acc[COT][PT];
  #pragma unroll
  for (int ct = 0; ct < COT; ++ct)
    #pragma unroll
    for (int pt = 0; pt < PT; ++pt)
      #pragma unroll
      for (int e = 0; e < 4; ++e) acc[ct][pt][e] = 0.f;

  int bbase[PT];
  #pragma unroll
  for (int pt = 0; pt < PT; ++pt) {
    int np = pos_off + pt * 16 + lane15;
    int ly = np / TW, lx = np % TW;
    bbase[pt] = (ly * XW + lx) * CS + quad * 8;
  }
  const _Float16* aptr[COT];
  #pragma unroll
  for (int ct = 0; ct < COT; ++ct)
    aptr[ct] = wb + (size_t)(coB + co_off + ct * 16 + lane15) * CIN + quad * 8;

  const _Float16* inb = in + (size_t)nb * H * W * CIN;

  for (int cc = 0; cc < NCC; ++cc) {
    constexpr int ITEMS = R * XW * 4;
    for (int i = t; i < ITEMS; i += 256) {
      int sub = i & 3, pix = i >> 2;
      int r = pix / XW, xx = pix % XW;
      int gy = y0 + r - P, gx = x0 + xx - P;
      half8 v;
      #pragma unroll
      for (int j = 0; j < 8; ++j) v[j] = (_Float16)0.f;
      if (gy >= 0 && gy < H && gx >= 0 && gx < W)
        v = *(const half8*)(inb + ((size_t)gy * W + gx) * CIN + cc * 32 + sub * 8);
      *(half8*)(&lds[pix * CS + sub * 8]) = v;
    }
    __syncthreads();
    #pragma unroll
    for (int tap = 0; tap < TAPS; ++tap) {
      int ky = tap / K, kx = tap % K;
      half8 a[COT], b[PT];
      #pragma unroll
      for (int ct = 0; ct < COT; ++ct)
        a[ct] = *(const half8*)(aptr[ct] + (size_t)tap * COUT * CIN + cc * 32);
      #pragma unroll
      for (int pt = 0; pt < PT; ++pt)
        b[pt] = *(const half8*)(&lds[bbase[pt] + (ky * XW + kx) * CS]);
      #pragma unroll
      for (int ct = 0; ct < COT; ++ct)
        #pragma unroll
        for (int pt = 0; pt < PT; ++pt)
          acc[ct][pt] = __builtin_amdgcn_mfma_f32_16x16x32_f16(
              a[ct], b[pt], acc[ct][pt], 0, 0, 0);
    }
    __syncthreads();
  }

  #pragma unroll
  for (int ct = 0; ct < COT; ++ct)
    #pragma unroll
    for (int pt = 0; pt < PT; ++pt) {
      int co = coB + co_off + ct * 16 + quad * 4;
      int np = pos_off + pt * 16 + lane15;
      int y = y0 + np / TW, x = x0 + np % TW;
      _Float16* op = out + (((size_t)nb * H + y) * W + x) * COUT + co;
      half4v h;
      #pragma unroll
      for (int e = 0; e < 4; ++e) h[e] = (_Float16)acc[ct][pt][e];
      *(half4v*)op = h;
    }
}

// ---------------- BN over NHWC f16 ------------------------------------------

__global__ __launch_bounds__(256)
void bn_stats_nhwc(const _Float16* __restrict__ x, float* __restrict__ stats,
                   int C, int HW) {
  __shared__ float r1[4][32], r2[4][32];
  int t = threadIdx.x;
  int cg = blockIdx.x, n = blockIdx.y, pz = blockIdx.z, PZ = gridDim.z;
  int c = cg * 32 + (t & 31);
  int pl = t >> 5;
  int chunk = HW / PZ;
  float s1 = 0.f, s2 = 0.f;
  for (int p = pz * chunk + pl; p < (pz + 1) * chunk; p += 8) {
    float v = (float)x[((size_t)n * HW + p) * C + c];
    s1 += v; s2 += v * v;
  }
  s1 += __shfl_down(s1, 32);
  s2 += __shfl_down(s2, 32);
  if ((t & 63) < 32) { r1[t >> 6][t & 31] = s1; r2[t >> 6][t & 31] = s2; }
  __syncthreads();
  if (t < 32) {
    atomicAdd(&stats[cg * 32 + t],     r1[0][t] + r1[1][t] + r1[2][t] + r1[3][t]);
    atomicAdd(&stats[C + cg * 32 + t], r2[0][t] + r2[1][t] + r2[2][t] + r2[3][t]);
  }
}

__global__ __launch_bounds__(256)
void bn_pool_nhwc(const _Float16* __restrict__ x, const float* __restrict__ stats,
                  const float* __restrict__ g, const float* __restrict__ bb,
                  _Float16* __restrict__ out, int C, int H, int W, float invN) {
  __shared__ float scs[256], shs[256];
  int t = threadIdx.x;
  int py = blockIdx.x, n = blockIdx.y;
  for (int c = t; c < C; c += 256) {
    float mean = stats[c] * invN;
    float var  = stats[C + c] * invN - mean * mean;
    float sc = g[c] / sqrtf(var + 1e-5f);
    scs[c] = sc; shs[c] = bb[c] - mean * sc;
  }
  __syncthreads();
  int W2 = W >> 1;
  int tot = W2 * C;
  for (int i = t; i < tot; i += 256) {
    int c = i % C, px = i / C;
    const _Float16* p0 = x + (((size_t)n * H + 2 * py) * W + 2 * px) * C + c;
    float sc = scs[c], sh = shs[c];
    float a = fmaxf((float)p0[0] * sc + sh, 0.f);
    float b = fmaxf((float)p0[C] * sc + sh, 0.f);
    float d = fmaxf((float)p0[(size_t)W * C] * sc + sh, 0.f);
    float e = fmaxf((float)p0[(size_t)W * C + C] * sc + sh, 0.f);
    out[(((size_t)n * (H / 2) + py) * W2 + px) * C + c] =
        (_Float16)fmaxf(fmaxf(a, b), fmaxf(d, e));
  }
}

__global__ __launch_bounds__(256)
void bn_relu_h16(const _Float16* __restrict__ x, const float* __restrict__ stats,
                 const float* __restrict__ g, const float* __restrict__ bb,
                 _Float16* __restrict__ out, int C, int HW, float invN) {
  __shared__ float scs[256], shs[256];
  int t = threadIdx.x;
  int n = blockIdx.y;
  for (int c = t; c < C; c += 256) {
    float mean = stats[c] * invN;
    float var  = stats[C + c] * invN - mean * mean;
    float sc = g[c] / sqrtf(var + 1e-5f);
    scs[c] = sc; shs[c] = bb[c] - mean * sc;
  }
  __syncthreads();
  int total = HW * C;
  int chunk = total / gridDim.x;
  int base = blockIdx.x * chunk;
  const _Float16* xp = x + (size_t)n * total;
  _Float16* op = out + (size_t)n * total;
  for (int i = base + t; i < base + chunk; i += 256) {
    int c = i % C;
    op[i] = (_Float16)fmaxf((float)xp[i] * scs[c] + shs[c], 0.f);
  }
}

__global__ __launch_bounds__(256)
void bn_avgpool_concat(const _Float16* __restrict__ x, const float* __restrict__ stats,
                       const float* __restrict__ g, const float* __restrict__ bb,
                       float* __restrict__ concat, float invN) {
  __shared__ float scs[128], shs[128];
  int t = threadIdx.x;
  int n = blockIdx.x;
  for (int c = t; c < 128; c += 256) {
    float mean = stats[c] * invN;
    float var  = stats[128 + c] * invN - mean * mean;
    float sc = g[c] / sqrtf(var + 1e-5f);
    scs[c] = sc; shs[c] = bb[c] - mean * sc;
  }
  __syncthreads();
  for (int i = t; i < 2048; i += 256) {
    int c = i & 127, opix = i >> 7;
    int py = opix >> 2, px = opix & 3;
    float sc = scs[c], sh = shs[c];
    float s = 0.f;
    for (int yy = 0; yy < 8; ++yy)
      for (int xx = 0; xx < 8; ++xx)
        s += fmaxf((float)x[(((size_t)n * 32 + py * 8 + yy) * 32 + px * 8 + xx) * 128 + c] * sc + sh, 0.f);
    concat[(size_t)n * 2112 + c * 16 + opix] = s * (1.f / 64.f);
  }
}

// ---------------- linear (one wave per output element) ----------------------

__global__ __launch_bounds__(64)
void linear_k(const float* __restrict__ in, const float* __restrict__ w,
              const float* __restrict__ bias, float* __restrict__ out,
              int I, int in_stride, int out_stride, int relu) {
  int o = blockIdx.x, b = blockIdx.y;
  int lane = threadIdx.x;
  const float* ip = in + (size_t)b * in_stride;
  const float* wp = w + (size_t)o * I;
  float acc = 0.f;
  for (int i = lane; i < I; i += 64) acc += ip[i] * wp[i];
  #pragma unroll
  for (int off = 32; off > 0; off >>= 1) acc += __shfl_down(acc, off);
  if (lane == 0) {
    float v = acc + bias[o];
    if (relu) v = fmaxf(v, 0.f);
    out[(size_t)b * out_stride + o] = v;
  }
}

// ---------------------------------------------------------------------------

extern "C" void kernel_launch(void* const* d_in, const int* in_sizes, int n_in,
                              void* d_out, int out_size, void* d_ws, size_t ws_size,
                              hipStream_t stream) {
  (void)in_sizes; (void)n_in; (void)out_size; (void)ws_size;
  const float* x   = (const float*)d_in[0];
  const float* cw1 = (const float*)d_in[1];
  const float* g1  = (const float*)d_in[3];
  const float* bb1 = (const float*)d_in[4];
  const float* cw2 = (const float*)d_in[5];
  const float* g2  = (const float*)d_in[7];
  const float* bb2 = (const float*)d_in[8];
  const float* cw3 = (const float*)d_in[9];
  const float* g3  = (const float*)d_in[11];
  const float* bb3 = (const float*)d_in[12];
  const float* cw4 = (const float*)d_in[13];
  const float* g4  = (const float*)d_in[15];
  const float* bb4 = (const float*)d_in[16];
  const float* pcw = (const float*)d_in[17];
  const float* pg  = (const float*)d_in[19];
  const float* pbb = (const float*)d_in[20];
  const float* pw1 = (const float*)d_in[21];
  const float* pb1 = (const float*)d_in[22];
  const float* pw2 = (const float*)d_in[23];
  const float* pb2 = (const float*)d_in[24];
  const float* pw3 = (const float*)d_in[25];
  const float* pb3 = (const float*)d_in[26];
  const float* fw1 = (const float*)d_in[27];
  const float* fb1 = (const float*)d_in[28];
  const float* fw2 = (const float*)d_in[29];
  const float* fb2 = (const float*)d_in[30];
  const float* fw3 = (const float*)d_in[31];
  const float* fb3 = (const float*)d_in[32];
  const float* fw4 = (const float*)d_in[33];
  const float* fb4 = (const float*)d_in[34];

  char* base = (char*)d_ws;
  // Region A (33.55 MB), time-multiplexed: fftbuf -> conv2o -> conv3o -> {conv4o, pconvo}
  float2*    fftbuf = (float2*)(base + 0);             // [16,256,256] cplx, 8.39 MB
  _Float16*  conv2o = (_Float16*)(base + 0);           // [16,128,128,64] 33.55 MB
  _Float16*  conv3o = (_Float16*)(base + 0);           // [16,64,64,128] 16.78 MB
  _Float16*  conv4o = (_Float16*)(base + 0);           // [16,32,32,256] 8.39 MB
  _Float16*  pconvo = (_Float16*)(base + 16777216);    // [16,32,32,128] 4.19 MB
  _Float16*  pool1  = (_Float16*)(base + 33554432);    // [16,128,128,32]
  _Float16*  pool2  = (_Float16*)(base + 50331648);    // [16,64,64,64]
  _Float16*  pool3  = (_Float16*)(base + 58720256);    // [16,32,32,128]
  _Float16*  act4   = (_Float16*)(base + 62914560);    // [16,32,32,256]
  _Float16*  wb2    = (_Float16*)(base + 71303168);    // 25*64*32
  _Float16*  wb3    = (_Float16*)(base + 71405568);    // 9*128*64
  _Float16*  wb4    = (_Float16*)(base + 71553024);    // 9*256*128
  _Float16*  wbp    = (_Float16*)(base + 72142848);    // 9*128*256
  float*     zbase  = (float*)(base + 72732672);       // 1728 floats
  float*     stats1 = zbase;            // 64
  float*     stats2 = zbase + 64;       // 128
  float*     stats3 = zbase + 192;      // 256
  float*     stats4 = zbase + 448;      // 512
  float*     stats5 = zbase + 960;      // 256
  float*     radial = zbase + 1216;     // 512
  float*     pf0    = (float*)(base + 72739584);
  float*     pf1    = (float*)(base + 72741632);
  float*     pf2    = (float*)(base + 72758016);
  float*     concat = (float*)(base + 72766208);       // 16*2112
  float*     fc1o   = (float*)(base + 72901376);
  float*     fc2o   = (float*)(base + 72934144);
  float*     fc3o   = (float*)(base + 72950528);

  hipMemsetAsync(zbase, 0, 1728 * sizeof(float), stream);

  // weight transforms
  wtrans<<<200,  256, 0, stream>>>(cw2, wb2, 64, 32, 25);
  wtrans<<<288,  256, 0, stream>>>(cw3, wb3, 128, 64, 9);
  wtrans<<<1152, 256, 0, stream>>>(cw4, wb4, 256, 128, 9);
  wtrans<<<1152, 256, 0, stream>>>(pcw, wbp, 128, 256, 9);

  // ---- FFT / power-features branch (region A dead until conv2) ----
  fft_rows<<<4096, 64, 0, stream>>>(x, fftbuf);
  fft_cols_radial_v2<<<512, 256, 0, stream>>>(fftbuf, radial);
  radial_finalize_v2<<<16, 64, 0, stream>>>(radial, pf0);
  linear_k<<<dim3(256, 16), 64, 0, stream>>>(pf0, pw1, pb1, pf1, 32, 32, 256, 1);
  linear_k<<<dim3(128, 16), 64, 0, stream>>>(pf1, pw2, pb2, pf2, 256, 256, 128, 1);
  linear_k<<<dim3(64, 16), 64, 0, stream>>>(pf2, pw3, pb3, concat + 2048, 128, 128, 2112, 1);

  // ---- conv1 ----
  conv1_stats_v2<<<dim3(32, 16), 256, 0, stream>>>(x, cw1, stats1);
  conv1_apply_v2<<<dim3(128, 16), 256, 0, stream>>>(x, cw1, stats1, g1, bb1, pool1);

  // ---- conv2: full 64 Cout, 16x8 spatial tile ----
  conv_mfma<32, 64, 128, 128, 5, 16, 8, 2, 4><<<dim3(128, 1, 16), 256, 0, stream>>>(
      pool1, wb2, conv2o);
  bn_stats_nhwc<<<dim3(2, 16, 8), 256, 0, stream>>>(conv2o, stats2, 64, 16384);
  bn_pool_nhwc<<<dim3(64, 16), 256, 0, stream>>>(
      conv2o, stats2, g2, bb2, pool2, 64, 128, 128, 1.f / 262144.f);

  // ---- conv3 ----
  conv_mfma<64, 128, 64, 64, 3, 8, 8, 4, 2><<<dim3(64, 1, 16), 256, 0, stream>>>(
      pool2, wb3, conv3o);
  bn_stats_nhwc<<<dim3(4, 16, 8), 256, 0, stream>>>(conv3o, stats3, 128, 4096);
  bn_pool_nhwc<<<dim3(32, 16), 256, 0, stream>>>(
      conv3o, stats3, g3, bb3, pool3, 128, 64, 64, 1.f / 65536.f);

  // ---- conv4 ----
  conv_mfma<128, 256, 32, 32, 3, 8, 8, 4, 2><<<dim3(16, 2, 16), 256, 0, stream>>>(
      pool3, wb4, conv4o);
  bn_stats_nhwc<<<dim3(8, 16, 8), 256, 0, stream>>>(conv4o, stats4, 256, 1024);
  bn_relu_h16<<<dim3(8, 16), 256, 0, stream>>>(
      conv4o, stats4, g4, bb4, act4, 256, 1024, 1.f / 16384.f);

  // ---- pconv ----
  conv_mfma<256, 128, 32, 32, 3, 4, 8, 4, 1><<<dim3(32, 1, 16), 256, 0, stream>>>(
      act4, wbp, pconvo);
  bn_stats_nhwc<<<dim3(4, 16, 8), 256, 0, stream>>>(pconvo, stats5, 128, 1024);
  bn_avgpool_concat<<<16, 256, 0, stream>>>(pconvo, stats5, pg, pbb, concat, 1.f / 16384.f);

  // ---- classifier head ----
  linear_k<<<dim3(512, 16), 64, 0, stream>>>(concat, fw1, fb1, fc1o, 2112, 2112, 512, 1);
  linear_k<<<dim3(256, 16), 64, 0, stream>>>(fc1o, fw2, fb2, fc2o, 512, 512, 256, 1);
  linear_k<<<dim3(128, 16), 64, 0, stream>>>(fc2o, fw3, fb3, fc3o, 256, 256, 128, 1);
  linear_k<<<dim3(2, 16), 64, 0, stream>>>(fc3o, fw4, fb4, (float*)d_out, 128, 128, 2, 0);
}

// Round 4
// 553.271 us; speedup vs baseline: 7.4896x; 1.2894x over previous
//
#include <hip/hip_runtime.h>
#include <math.h>

// ---------------------------------------------------------------------------
// R4: convs 2-5 implicit-GEMM MFMA (f16 in/out, fp32 accum) with FUSED BN
// stats in the epilogue. conv1 via float4 register-window (v_pk_fma). Radial
// bin counts: one block per bin. MLP chains fused. 18 dispatches total.
// MFMA 16x16x32 f16: A m=lane&15,k=quad*8+j; B n=lane&15,k=quad*8+j;
//                    D col(n)=lane&15, row(m)=quad*4+reg.
// ---------------------------------------------------------------------------

#define PI2F 6.283185307179586f

typedef _Float16 half8 __attribute__((ext_vector_type(8)));
typedef _Float16 half4v __attribute__((ext_vector_type(4)));
typedef float f32x4 __attribute__((ext_vector_type(4)));

// ---------------- FFT branch ------------------------------------------------

__device__ __forceinline__ int bitrev8(int x) {
  x = ((x & 0x0F) << 4) | ((x >> 4) & 0x0F);
  x = ((x & 0x33) << 2) | ((x >> 2) & 0x33);
  x = ((x & 0x55) << 1) | ((x >> 1) & 0x55);
  return x;
}

__global__ __launch_bounds__(64)
void fft_rows(const float* __restrict__ x, float2* __restrict__ out) {
  __shared__ float2 s[256];
  __shared__ float2 tw[128];
  int blk = blockIdx.x;
  const float* rowp = x + (size_t)blk * 256;
  int t = threadIdx.x;
  for (int i = t; i < 128; i += 64) {
    float sn, cs;
    sincosf(-(PI2F / 256.f) * (float)i, &sn, &cs);
    tw[i] = make_float2(cs, sn);
  }
  #pragma unroll
  for (int e = 0; e < 4; ++e) {
    int i = t + (e << 6);
    s[bitrev8(i)] = make_float2(rowp[i], 0.f);
  }
  __syncthreads();
  #pragma unroll
  for (int st = 1; st <= 8; ++st) {
    int half = 1 << (st - 1);
    #pragma unroll
    for (int j = 0; j < 2; ++j) {
      int bf = t + (j << 6);
      int pos = bf & (half - 1);
      int grp = bf >> (st - 1);
      int i0 = (grp << st) | pos;
      int i1 = i0 + half;
      int k = pos << (8 - st);
      float cs = tw[k].x, sn = tw[k].y;
      float2 a = s[i0], b = s[i1];
      float tr = cs * b.x - sn * b.y;
      float ti = cs * b.y + sn * b.x;
      s[i0] = make_float2(a.x + tr, a.y + ti);
      s[i1] = make_float2(a.x - tr, a.y - ti);
    }
    __syncthreads();
  }
  float2* op = out + (size_t)blk * 256;
  #pragma unroll
  for (int e = 0; e < 4; ++e) { int i = t + (e << 6); op[i] = s[i]; }
}

__device__ __forceinline__ int radial_bin(int r2) {
  int j = (int)(sqrtf((float)r2) * 0.25f);
  while ((j + 1) * (j + 1) * 16 <= r2) ++j;
  while (j > 0 && j * j * 16 > r2) --j;
  return j;
}

__global__ __launch_bounds__(256)
void fft_cols_radial_v2(const float2* __restrict__ f, float* __restrict__ radial) {
  __shared__ float2 s[8][258];
  __shared__ float2 tw[128];
  __shared__ float bins[8][32];
  int b = blockIdx.x >> 5;
  int col0 = (blockIdx.x & 31) * 8;
  int t = threadIdx.x;
  for (int i = t; i < 128; i += 256) {
    float sn, cs;
    sincosf(-(PI2F / 256.f) * (float)i, &sn, &cs);
    tw[i] = make_float2(cs, sn);
  }
  ((float*)bins)[t] = 0.f;
  for (int idx = t; idx < 2048; idx += 256) {
    int row = idx >> 3, c = idx & 7;
    s[c][bitrev8(row)] = f[(size_t)b * 65536 + row * 256 + col0 + c];
  }
  __syncthreads();
  int c = t >> 5, l = t & 31;
  float2* sc = &s[c][0];
  #pragma unroll
  for (int st = 1; st <= 8; ++st) {
    int half = 1 << (st - 1);
    #pragma unroll
    for (int j = 0; j < 4; ++j) {
      int bf = l + (j << 5);
      int pos = bf & (half - 1);
      int grp = bf >> (st - 1);
      int i0 = (grp << st) | pos;
      int i1 = i0 + half;
      int k = pos << (8 - st);
      float cs = tw[k].x, sn = tw[k].y;
      float2 a = sc[i0], bb = sc[i1];
      float tr = cs * bb.x - sn * bb.y;
      float ti = cs * bb.y + sn * bb.x;
      sc[i0] = make_float2(a.x + tr, a.y + ti);
      sc[i1] = make_float2(a.x - tr, a.y - ti);
    }
    __syncthreads();
  }
  int dx = col0 + c - 128;
  #pragma unroll
  for (int e = 0; e < 8; ++e) {
    int i = l * 8 + e;
    float2 v = sc[i];
    float ps = v.x * v.x + v.y * v.y;
    int dy = i - 128;
    int r2 = dx * dx + dy * dy;
    if (r2 < 16384) atomicAdd(&bins[c][radial_bin(r2)], ps);
  }
  __syncthreads();
  if (t < 32) {
    float s0 = bins[0][t] + bins[1][t] + bins[2][t] + bins[3][t] +
               bins[4][t] + bins[5][t] + bins[6][t] + bins[7][t];
    atomicAdd(&radial[b * 32 + t], s0);
  }
}

__device__ __forceinline__ int isqrt_(int v) {
  int r = (int)sqrtf((float)v);
  while (r * r > v) --r;
  while ((r + 1) * (r + 1) <= v) ++r;
  return r;
}

// one block per bin; one dy per thread; block-reduce the count
__global__ __launch_bounds__(256)
void radial_finalize_v3(const float* __restrict__ radial, float* __restrict__ pf0) {
  __shared__ int red[4];
  __shared__ int cnt_s;
  int j = blockIdx.x, t = threadIdx.x;
  int dy = t - 128;
  int lo = 16 * j * j, hi = 16 * (j + 1) * (j + 1);
  int d2 = dy * dy;
  int cnt = 0;
  int tHi = hi - 1 - d2;
  if (tHi >= 0) {
    int rHi = isqrt_(tHi);
    int nHi = min(rHi, 127) + min(rHi, 128) + 1;
    int nLo = 0;
    int tLo = lo - 1 - d2;
    if (tLo >= 0) { int rLo = isqrt_(tLo); nLo = min(rLo, 127) + min(rLo, 128) + 1; }
    cnt = nHi - nLo;
  }
  #pragma unroll
  for (int off = 32; off > 0; off >>= 1) cnt += __shfl_down(cnt, off);
  if ((t & 63) == 0) red[t >> 6] = cnt;
  __syncthreads();
  if (t == 0) cnt_s = red[0] + red[1] + red[2] + red[3];
  __syncthreads();
  if (t < 16) {
    float cf = (float)cnt_s;
    float sum = radial[t * 32 + j];
    float val = cf > 0.f ? sum / fmaxf(cf, 1.f) : 0.f;
    pf0[t * 32 + j] = logf(val + 1e-10f);
  }
}

// ---------------- weight transforms (all four in one kernel) ----------------

__global__ __launch_bounds__(256)
void wtrans_all(const float* __restrict__ cw2, const float* __restrict__ cw3,
                const float* __restrict__ cw4, const float* __restrict__ pcw,
                _Float16* __restrict__ wb2, _Float16* __restrict__ wb3,
                _Float16* __restrict__ wb4, _Float16* __restrict__ wbp) {
  int blk = blockIdx.x;
  const float* src; _Float16* dst; int COUT, CIN, KK, i;
  if (blk < 200)       { src = cw2; dst = wb2; COUT = 64;  CIN = 32;  KK = 25; i = blk * 256; }
  else if (blk < 488)  { src = cw3; dst = wb3; COUT = 128; CIN = 64;  KK = 9;  i = (blk - 200) * 256; }
  else if (blk < 1640) { src = cw4; dst = wb4; COUT = 256; CIN = 128; KK = 9;  i = (blk - 488) * 256; }
  else                 { src = pcw; dst = wbp; COUT = 128; CIN = 256; KK = 9;  i = (blk - 1640) * 256; }
  i += threadIdx.x;
  if (i >= COUT * CIN * KK) return;
  int ci = i % CIN;
  int r = i / CIN;
  int co = r % COUT;
  int tap = r / COUT;
  dst[i] = (_Float16)src[((size_t)co * CIN + ci) * KK + tap];
}

// ---------------- conv1 (Cin=1, 5x5): float4 register-window ----------------

__device__ __forceinline__ void load16(float* d, const float* p) {
  f32x4 v0 = *(const f32x4*)(p);
  f32x4 v1 = *(const f32x4*)(p + 4);
  f32x4 v2 = *(const f32x4*)(p + 8);
  f32x4 v3 = *(const f32x4*)(p + 12);
  #pragma unroll
  for (int e = 0; e < 4; ++e) { d[e] = v0[e]; d[4+e] = v1[e]; d[8+e] = v2[e]; d[12+e] = v3[e]; }
}

__global__ __launch_bounds__(256)
void conv1_stats_v3(const float* __restrict__ x, const float* __restrict__ w,
                    float* __restrict__ stats) {
  __shared__ float lds[12 * 264];
  __shared__ float r1[4][32], r2[4][32];
  int t = threadIdx.x;
  int y0 = blockIdx.x * 8, n = blockIdx.y;
  const float* xp = x + (size_t)n * 65536;
  for (int i = t; i < 12 * 264; i += 256) {
    int r = i / 264, cc = i % 264;
    int gy = y0 + r - 2, gx = cc - 4;
    lds[i] = (gy >= 0 && gy < 256 && gx >= 0 && gx < 256) ? xp[gy * 256 + gx] : 0.f;
  }
  __syncthreads();
  int c = t & 31, xg = t >> 5;
  float wreg[25];
  #pragma unroll
  for (int k = 0; k < 25; ++k) wreg[k] = w[c * 25 + k];
  float s1 = 0.f, s2 = 0.f;
  for (int strip = 0; strip < 4; ++strip) {
    int px0 = xg * 8 + strip * 64;      // output cols px0..px0+7; lds idx = col+4
    float f[5][16];
    #pragma unroll
    for (int rr = 0; rr < 4; ++rr) load16(f[rr], &lds[rr * 264 + px0]);
    #pragma unroll
    for (int r = 0; r < 8; ++r) {
      load16(f[(r + 4) % 5], &lds[(r + 4) * 264 + px0]);
      f32x4 A = {0.f, 0.f, 0.f, 0.f}, B = {0.f, 0.f, 0.f, 0.f};
      #pragma unroll
      for (int ky = 0; ky < 5; ++ky) {
        const float* fr = f[(r + ky) % 5];
        #pragma unroll
        for (int kx = 0; kx < 5; ++kx) {
          float wv = wreg[ky * 5 + kx];
          f32x4 ia = {fr[2 + kx], fr[3 + kx], fr[4 + kx], fr[5 + kx]};
          f32x4 ib = {fr[6 + kx], fr[7 + kx], fr[8 + kx], fr[9 + kx]};
          A += wv * ia; B += wv * ib;
        }
      }
      s1 += A[0] + A[1] + A[2] + A[3] + B[0] + B[1] + B[2] + B[3];
      s2 += A[0]*A[0] + A[1]*A[1] + A[2]*A[2] + A[3]*A[3]
          + B[0]*B[0] + B[1]*B[1] + B[2]*B[2] + B[3]*B[3];
    }
  }
  s1 += __shfl_down(s1, 32);
  s2 += __shfl_down(s2, 32);
  if ((t & 63) < 32) { r1[t >> 6][t & 31] = s1; r2[t >> 6][t & 31] = s2; }
  __syncthreads();
  if (t < 32) {
    atomicAdd(&stats[t],      r1[0][t] + r1[1][t] + r1[2][t] + r1[3][t]);
    atomicAdd(&stats[32 + t], r2[0][t] + r2[1][t] + r2[2][t] + r2[3][t]);
  }
}

__global__ __launch_bounds__(256)
void conv1_apply_v3(const float* __restrict__ x, const float* __restrict__ w,
                    const float* __restrict__ stats, const float* __restrict__ g,
                    const float* __restrict__ bb, _Float16* __restrict__ pool1) {
  __shared__ float lds[6 * 264];
  int t = threadIdx.x;
  int py = blockIdx.x, n = blockIdx.y;
  const float* xp = x + (size_t)n * 65536;
  for (int i = t; i < 6 * 264; i += 256) {
    int r = i / 264, cc = i % 264;
    int gy = 2 * py + r - 2, gx = cc - 4;
    lds[i] = (gy >= 0 && gy < 256 && gx >= 0 && gx < 256) ? xp[gy * 256 + gx] : 0.f;
  }
  __syncthreads();
  int c = t & 31, xg = t >> 5;
  float wreg[25];
  #pragma unroll
  for (int k = 0; k < 25; ++k) wreg[k] = w[c * 25 + k];
  float mean = stats[c] * (1.f / 1048576.f);
  float var  = stats[32 + c] * (1.f / 1048576.f) - mean * mean;
  float sc = g[c] / sqrtf(var + 1e-5f);
  float sh = bb[c] - mean * sc;
  for (int iter = 0; iter < 4; ++iter) {
    int p0 = xg * 4 + iter * 32;        // 4 pooled outputs p0..p0+3
    float f[6][16];
    #pragma unroll
    for (int rr = 0; rr < 6; ++rr) load16(f[rr], &lds[rr * 264 + 2 * p0]);
    f32x4 acc[2][2];
    #pragma unroll
    for (int sy = 0; sy < 2; ++sy)
      #pragma unroll
      for (int h = 0; h < 2; ++h) acc[sy][h] = (f32x4){0.f, 0.f, 0.f, 0.f};
    #pragma unroll
    for (int sy = 0; sy < 2; ++sy)
      #pragma unroll
      for (int ky = 0; ky < 5; ++ky) {
        const float* fr = f[sy + ky];
        #pragma unroll
        for (int kx = 0; kx < 5; ++kx) {
          float wv = wreg[ky * 5 + kx];
          f32x4 ia = {fr[2 + kx], fr[3 + kx], fr[4 + kx], fr[5 + kx]};
          f32x4 ib = {fr[6 + kx], fr[7 + kx], fr[8 + kx], fr[9 + kx]};
          acc[sy][0] += wv * ia; acc[sy][1] += wv * ib;
        }
      }
    #pragma unroll
    for (int pp = 0; pp < 4; ++pp) {
      float v00 = acc[0][(2*pp) >> 2][(2*pp) & 3];
      float v01 = acc[0][(2*pp+1) >> 2][(2*pp+1) & 3];
      float v10 = acc[1][(2*pp) >> 2][(2*pp) & 3];
      float v11 = acc[1][(2*pp+1) >> 2][(2*pp+1) & 3];
      float m = fmaxf(fmaxf(v00, v01), fmaxf(v10, v11));
      pool1[(((size_t)n * 128 + py) * 128 + p0 + pp) * 32 + c] =
          (_Float16)fmaxf(m * sc + sh, 0.f);
    }
  }
}

// ---------------- implicit-GEMM MFMA conv + fused BN stats ------------------

template <int CIN, int COUT, int H, int W, int K, int TH, int TW, int COT, int PT>
__global__ __launch_bounds__(256)
void conv_mfma(const _Float16* __restrict__ in, const _Float16* __restrict__ wb,
               _Float16* __restrict__ out, float* __restrict__ stats) {
  constexpr int P = K / 2, R = TH + 2 * P, XW = TW + 2 * P;
  constexpr int TAPS = K * K, NCC = CIN / 32, CS = 40;
  static_assert(TH * TW == 32 * PT, "pos tile mismatch");
  __shared__ _Float16 lds[R * XW * CS];
  __shared__ float sst[2][32 * COT];
  int t = threadIdx.x;
  int lane = t & 63, wv = t >> 6;
  int lane15 = lane & 15, quad = lane >> 4;
  constexpr int WT = W / TW;
  int x0 = (blockIdx.x % WT) * TW, y0 = (blockIdx.x / WT) * TH;
  int coB = blockIdx.y * (32 * COT);
  int nb = blockIdx.z;
  int co_off = (wv & 1) * (16 * COT);
  int pos_off = (wv >> 1) * (16 * PT);

  for (int i = t; i < 64 * COT; i += 256) ((float*)sst)[i] = 0.f;

  f32x4 acc[COT][PT];
  #pragma unroll
  for (int ct = 0; ct < COT; ++ct)
    #pragma unroll
    for (int pt = 0; pt < PT; ++pt)
      #pragma unroll
      for (int e = 0; e < 4; ++e) acc[ct][pt][e] = 0.f;

  int bbase[PT];
  #pragma unroll
  for (int pt = 0; pt < PT; ++pt) {
    int np = pos_off + pt * 16 + lane15;
    int ly = np / TW, lx = np % TW;
    bbase[pt] = (ly * XW + lx) * CS + quad * 8;
  }
  const _Float16* aptr[COT];
  #pragma unroll
  for (int ct = 0; ct < COT; ++ct)
    aptr[ct] = wb + (size_t)(coB + co_off + ct * 16 + lane15) * CIN + quad * 8;

  const _Float16* inb = in + (size_t)nb * H * W * CIN;

  for (int cc = 0; cc < NCC; ++cc) {
    constexpr int ITEMS = R * XW * 4;
    for (int i = t; i < ITEMS; i += 256) {
      int sub = i & 3, pix = i >> 2;
      int r = pix / XW, xx = pix % XW;
      int gy = y0 + r - P, gx = x0 + xx - P;
      half8 v;
      #pragma unroll
      for (int j = 0; j < 8; ++j) v[j] = (_Float16)0.f;
      if (gy >= 0 && gy < H && gx >= 0 && gx < W)
        v = *(const half8*)(inb + ((size_t)gy * W + gx) * CIN + cc * 32 + sub * 8);
      *(half8*)(&lds[pix * CS + sub * 8]) = v;
    }
    __syncthreads();
    #pragma unroll
    for (int tap = 0; tap < TAPS; ++tap) {
      int ky = tap / K, kx = tap % K;
      half8 a[COT], b[PT];
      #pragma unroll
      for (int ct = 0; ct < COT; ++ct)
        a[ct] = *(const half8*)(aptr[ct] + (size_t)tap * COUT * CIN + cc * 32);
      #pragma unroll
      for (int pt = 0; pt < PT; ++pt)
        b[pt] = *(const half8*)(&lds[bbase[pt] + (ky * XW + kx) * CS]);
      #pragma unroll
      for (int ct = 0; ct < COT; ++ct)
        #pragma unroll
        for (int pt = 0; pt < PT; ++pt)
          acc[ct][pt] = __builtin_amdgcn_mfma_f32_16x16x32_f16(
              a[ct], b[pt], acc[ct][pt], 0, 0, 0);
    }
    __syncthreads();
  }

  // store + fused BN stats
  #pragma unroll
  for (int ct = 0; ct < COT; ++ct)
    #pragma unroll
    for (int pt = 0; pt < PT; ++pt) {
      int co = coB + co_off + ct * 16 + quad * 4;
      int np = pos_off + pt * 16 + lane15;
      int y = y0 + np / TW, x = x0 + np % TW;
      _Float16* op = out + (((size_t)nb * H + y) * W + x) * COUT + co;
      half4v h;
      #pragma unroll
      for (int e = 0; e < 4; ++e) h[e] = (_Float16)acc[ct][pt][e];
      *(half4v*)op = h;
    }
  #pragma unroll
  for (int ct = 0; ct < COT; ++ct)
    #pragma unroll
    for (int e = 0; e < 4; ++e) {
      float sv = 0.f, sq = 0.f;
      #pragma unroll
      for (int pt = 0; pt < PT; ++pt) {
        float v = acc[ct][pt][e];
        sv += v; sq += v * v;
      }
      sv += __shfl_xor(sv, 1); sq += __shfl_xor(sq, 1);
      sv += __shfl_xor(sv, 2); sq += __shfl_xor(sq, 2);
      sv += __shfl_xor(sv, 4); sq += __shfl_xor(sq, 4);
      sv += __shfl_xor(sv, 8); sq += __shfl_xor(sq, 8);
      if (lane15 == 0) {
        int cl = co_off + ct * 16 + quad * 4 + e;
        atomicAdd(&sst[0][cl], sv);
        atomicAdd(&sst[1][cl], sq);
      }
    }
  __syncthreads();
  for (int i = t; i < 32 * COT; i += 256) {
    atomicAdd(&stats[coB + i], sst[0][i]);
    atomicAdd(&stats[COUT + coB + i], sst[1][i]);
  }
}

// ---------------- BN epilogues (read fused stats) ---------------------------

__global__ __launch_bounds__(256)
void bn_pool_nhwc(const _Float16* __restrict__ x, const float* __restrict__ stats,
                  const float* __restrict__ g, const float* __restrict__ bb,
                  _Float16* __restrict__ out, int C, int H, int W, float invN) {
  __shared__ float scs[256], shs[256];
  int t = threadIdx.x;
  int py = blockIdx.x, n = blockIdx.y;
  for (int c = t; c < C; c += 256) {
    float mean = stats[c] * invN;
    float var  = stats[C + c] * invN - mean * mean;
    float sc = g[c] / sqrtf(var + 1e-5f);
    scs[c] = sc; shs[c] = bb[c] - mean * sc;
  }
  __syncthreads();
  int W2 = W >> 1;
  int tot = W2 * C;
  for (int i = t; i < tot; i += 256) {
    int c = i % C, px = i / C;
    const _Float16* p0 = x + (((size_t)n * H + 2 * py) * W + 2 * px) * C + c;
    float sc = scs[c], sh = shs[c];
    float a = fmaxf((float)p0[0] * sc + sh, 0.f);
    float b = fmaxf((float)p0[C] * sc + sh, 0.f);
    float d = fmaxf((float)p0[(size_t)W * C] * sc + sh, 0.f);
    float e = fmaxf((float)p0[(size_t)W * C + C] * sc + sh, 0.f);
    out[(((size_t)n * (H / 2) + py) * W2 + px) * C + c] =
        (_Float16)fmaxf(fmaxf(a, b), fmaxf(d, e));
  }
}

__global__ __launch_bounds__(256)
void bn_relu_h16(const _Float16* __restrict__ x, const float* __restrict__ stats,
                 const float* __restrict__ g, const float* __restrict__ bb,
                 _Float16* __restrict__ out, int C, int HW, float invN) {
  __shared__ float scs[256], shs[256];
  int t = threadIdx.x;
  int n = blockIdx.y;
  for (int c = t; c < C; c += 256) {
    float mean = stats[c] * invN;
    float var  = stats[C + c] * invN - mean * mean;
    float sc = g[c] / sqrtf(var + 1e-5f);
    scs[c] = sc; shs[c] = bb[c] - mean * sc;
  }
  __syncthreads();
  int total = HW * C;
  int chunk = total / gridDim.x;
  int base = blockIdx.x * chunk;
  const _Float16* xp = x + (size_t)n * total;
  _Float16* op = out + (size_t)n * total;
  for (int i = base + t; i < base + chunk; i += 256) {
    int c = i % C;
    op[i] = (_Float16)fmaxf((float)xp[i] * scs[c] + shs[c], 0.f);
  }
}

__global__ __launch_bounds__(256)
void bn_avgpool_concat(const _Float16* __restrict__ x, const float* __restrict__ stats,
                       const float* __restrict__ g, const float* __restrict__ bb,
                       float* __restrict__ concat, float invN) {
  __shared__ float scs[128], shs[128];
  int t = threadIdx.x;
  int n = blockIdx.x;
  for (int c = t; c < 128; c += 256) {
    float mean = stats[c] * invN;
    float var  = stats[128 + c] * invN - mean * mean;
    float sc = g[c] / sqrtf(var + 1e-5f);
    scs[c] = sc; shs[c] = bb[c] - mean * sc;
  }
  __syncthreads();
  for (int i = t; i < 2048; i += 256) {
    int c = i & 127, opix = i >> 7;
    int py = opix >> 2, px = opix & 3;
    float sc = scs[c], sh = shs[c];
    float s = 0.f;
    for (int yy = 0; yy < 8; ++yy)
      for (int xx = 0; xx < 8; ++xx)
        s += fmaxf((float)x[(((size_t)n * 32 + py * 8 + yy) * 32 + px * 8 + xx) * 128 + c] * sc + sh, 0.f);
    concat[(size_t)n * 2112 + c * 16 + opix] = s * (1.f / 64.f);
  }
}

// ---------------- MLP heads -------------------------------------------------

__global__ __launch_bounds__(64)
void linear_k(const float* __restrict__ in, const float* __restrict__ w,
              const float* __restrict__ bias, float* __restrict__ out,
              int I, int in_stride, int out_stride, int relu) {
  int o = blockIdx.x, b = blockIdx.y;
  int lane = threadIdx.x;
  const float* ip = in + (size_t)b * in_stride;
  const float* wp = w + (size_t)o * I;
  float acc = 0.f;
  for (int i = lane; i < I; i += 64) acc += ip[i] * wp[i];
  #pragma unroll
  for (int off = 32; off > 0; off >>= 1) acc += __shfl_down(acc, off);
  if (lane == 0) {
    float v = acc + bias[o];
    if (relu) v = fmaxf(v, 0.f);
    out[(size_t)b * out_stride + o] = v;
  }
}

// pf chain fused: 32 -> 256 -> 128 -> 64, one block per image
__global__ __launch_bounds__(256)
void pf_mlp(const float* __restrict__ pf0,
            const float* __restrict__ pw1, const float* __restrict__ pb1,
            const float* __restrict__ pw2, const float* __restrict__ pb2,
            const float* __restrict__ pw3, const float* __restrict__ pb3,
            float* __restrict__ concat) {
  __shared__ float a0[32], a1[256], a2[128];
  int b = blockIdx.x, t = threadIdx.x;
  if (t < 32) a0[t] = pf0[b * 32 + t];
  __syncthreads();
  {
    float s = pb1[t];
    for (int i = 0; i < 32; ++i) s += pw1[t * 32 + i] * a0[i];
    a1[t] = fmaxf(s, 0.f);
  }
  __syncthreads();
  if (t < 128) {
    float s = pb2[t];
    for (int i = 0; i < 256; ++i) s += pw2[t * 256 + i] * a1[i];
    a2[t] = fmaxf(s, 0.f);
  }
  __syncthreads();
  if (t < 64) {
    float s = pb3[t];
    for (int i = 0; i < 128; ++i) s += pw3[t * 128 + i] * a2[i];
    concat[(size_t)b * 2112 + 2048 + t] = fmaxf(s, 0.f);
  }
}

// fc tail fused: 512 -> 256 -> 128 -> 2, one block per image
__global__ __launch_bounds__(256)
void fc_tail(const float* __restrict__ fc1o,
             const float* __restrict__ fw2, const float* __restrict__ fb2,
             const float* __restrict__ fw3, const float* __restrict__ fb3,
             const float* __restrict__ fw4, const float* __restrict__ fb4,
             float* __restrict__ out) {
  __shared__ float a1[512], a2[256], a3[128];
  int b = blockIdx.x, t = threadIdx.x;
  a1[t] = fc1o[b * 512 + t];
  a1[t + 256] = fc1o[b * 512 + t + 256];
  __syncthreads();
  {
    float s = fb2[t];
    for (int i = 0; i < 512; ++i) s += fw2[t * 512 + i] * a1[i];
    a2[t] = fmaxf(s, 0.f);
  }
  __syncthreads();
  if (t < 128) {
    float s = fb3[t];
    for (int i = 0; i < 256; ++i) s += fw3[t * 256 + i] * a2[i];
    a3[t] = fmaxf(s, 0.f);
  }
  __syncthreads();
  if (t < 2) {
    float s = fb4[t];
    for (int i = 0; i < 128; ++i) s += fw4[t * 128 + i] * a3[i];
    out[b * 2 + t] = s;
  }
}

// ---------------------------------------------------------------------------

extern "C" void kernel_launch(void* const* d_in, const int* in_sizes, int n_in,
                              void* d_out, int out_size, void* d_ws, size_t ws_size,
                              hipStream_t stream) {
  (void)in_sizes; (void)n_in; (void)out_size; (void)ws_size;
  const float* x   = (const float*)d_in[0];
  const float* cw1 = (const float*)d_in[1];
  const float* g1  = (const float*)d_in[3];
  const float* bb1 = (const float*)d_in[4];
  const float* cw2 = (const float*)d_in[5];
  const float* g2  = (const float*)d_in[7];
  const float* bb2 = (const float*)d_in[8];
  const float* cw3 = (const float*)d_in[9];
  const float* g3  = (const float*)d_in[11];
  const float* bb3 = (const float*)d_in[12];
  const float* cw4 = (const float*)d_in[13];
  const float* g4  = (const float*)d_in[15];
  const float* bb4 = (const float*)d_in[16];
  const float* pcw = (const float*)d_in[17];
  const float* pg  = (const float*)d_in[19];
  const float* pbb = (const float*)d_in[20];
  const float* pw1 = (const float*)d_in[21];
  const float* pb1 = (const float*)d_in[22];
  const float* pw2 = (const float*)d_in[23];
  const float* pb2 = (const float*)d_in[24];
  const float* pw3 = (const float*)d_in[25];
  const float* pb3 = (const float*)d_in[26];
  const float* fw1 = (const float*)d_in[27];
  const float* fb1 = (const float*)d_in[28];
  const float* fw2 = (const float*)d_in[29];
  const float* fb2 = (const float*)d_in[30];
  const float* fw3 = (const float*)d_in[31];
  const float* fb3 = (const float*)d_in[32];
  const float* fw4 = (const float*)d_in[33];
  const float* fb4 = (const float*)d_in[34];

  char* base = (char*)d_ws;
  float2*    fftbuf = (float2*)(base + 0);             // [16,256,256] cplx
  _Float16*  conv2o = (_Float16*)(base + 0);           // [16,128,128,64]
  _Float16*  conv3o = (_Float16*)(base + 0);           // [16,64,64,128]
  _Float16*  conv4o = (_Float16*)(base + 0);           // [16,32,32,256]
  _Float16*  pconvo = (_Float16*)(base + 16777216);    // [16,32,32,128]
  _Float16*  pool1  = (_Float16*)(base + 33554432);    // [16,128,128,32]
  _Float16*  pool2  = (_Float16*)(base + 50331648);    // [16,64,64,64]
  _Float16*  pool3  = (_Float16*)(base + 58720256);    // [16,32,32,128]
  _Float16*  act4   = (_Float16*)(base + 62914560);    // [16,32,32,256]
  _Float16*  wb2    = (_Float16*)(base + 71303168);
  _Float16*  wb3    = (_Float16*)(base + 71405568);
  _Float16*  wb4    = (_Float16*)(base + 71553024);
  _Float16*  wbp    = (_Float16*)(base + 72142848);
  float*     zbase  = (float*)(base + 72732672);       // 1728 floats
  float*     stats1 = zbase;            // 64
  float*     stats2 = zbase + 64;       // 128
  float*     stats3 = zbase + 192;      // 256
  float*     stats4 = zbase + 448;      // 512
  float*     stats5 = zbase + 960;      // 256
  float*     radial = zbase + 1216;     // 512
  float*     pf0    = (float*)(base + 72739584);
  float*     concat = (float*)(base + 72766208);       // 16*2112
  float*     fc1o   = (float*)(base + 72901376);

  hipMemsetAsync(zbase, 0, 1728 * sizeof(float), stream);

  wtrans_all<<<2792, 256, 0, stream>>>(cw2, cw3, cw4, pcw, wb2, wb3, wb4, wbp);

  // ---- FFT / power-features branch (fftbuf aliases conv region) ----
  fft_rows<<<4096, 64, 0, stream>>>(x, fftbuf);
  fft_cols_radial_v2<<<512, 256, 0, stream>>>(fftbuf, radial);
  radial_finalize_v3<<<32, 256, 0, stream>>>(radial, pf0);
  pf_mlp<<<16, 256, 0, stream>>>(pf0, pw1, pb1, pw2, pb2, pw3, pb3, concat);

  // ---- conv1 ----
  conv1_stats_v3<<<dim3(32, 16), 256, 0, stream>>>(x, cw1, stats1);
  conv1_apply_v3<<<dim3(128, 16), 256, 0, stream>>>(x, cw1, stats1, g1, bb1, pool1);

  // ---- conv2 ----
  conv_mfma<32, 64, 128, 128, 5, 16, 8, 2, 4><<<dim3(128, 1, 16), 256, 0, stream>>>(
      pool1, wb2, conv2o, stats2);
  bn_pool_nhwc<<<dim3(64, 16), 256, 0, stream>>>(
      conv2o, stats2, g2, bb2, pool2, 64, 128, 128, 1.f / 262144.f);

  // ---- conv3 ----
  conv_mfma<64, 128, 64, 64, 3, 8, 8, 4, 2><<<dim3(64, 1, 16), 256, 0, stream>>>(
      pool2, wb3, conv3o, stats3);
  bn_pool_nhwc<<<dim3(32, 16), 256, 0, stream>>>(
      conv3o, stats3, g3, bb3, pool3, 128, 64, 64, 1.f / 65536.f);

  // ---- conv4 ----
  conv_mfma<128, 256, 32, 32, 3, 8, 8, 4, 2><<<dim3(16, 2, 16), 256, 0, stream>>>(
      pool3, wb4, conv4o, stats4);
  bn_relu_h16<<<dim3(8, 16), 256, 0, stream>>>(
      conv4o, stats4, g4, bb4, act4, 256, 1024, 1.f / 16384.f);

  // ---- pconv ----
  conv_mfma<256, 128, 32, 32, 3, 4, 8, 4, 1><<<dim3(32, 1, 16), 256, 0, stream>>>(
      act4, wbp, pconvo, stats5);
  bn_avgpool_concat<<<16, 256, 0, stream>>>(pconvo, stats5, pg, pbb, concat, 1.f / 16384.f);

  // ---- classifier head ----
  linear_k<<<dim3(512, 16), 64, 0, stream>>>(concat, fw1, fb1, fc1o, 2112, 2112, 512, 1);
  fc_tail<<<16, 256, 0, stream>>>(fc1o, fw2, fb2, fw3, fb3, fw4, fb4, (float*)d_out);
}

// Round 5
// 453.385 us; speedup vs baseline: 9.1397x; 1.2203x over previous
//
#include <hip/hip_runtime.h>
#include <math.h>

// ---------------------------------------------------------------------------
// R5: convs 2-5 as single-K-slab implicit-GEMM MFMA: whole ci range of the
// spatial tile staged to LDS once (1 barrier; pconv: 2 slabs), long MFMA loop
// from LDS. Fused BN stats spread over 8 atomic slices. f16 in/out, fp32 acc.
// MFMA 16x16x32 f16: A m=lane&15,k=quad*8+j; B n=lane&15,k=quad*8+j;
//                    D col(n)=lane&15, row(m)=quad*4+reg.
// ---------------------------------------------------------------------------

#define PI2F 6.283185307179586f

typedef _Float16 half8 __attribute__((ext_vector_type(8)));
typedef _Float16 half4v __attribute__((ext_vector_type(4)));
typedef float f32x4 __attribute__((ext_vector_type(4)));

// ---------------- FFT branch ------------------------------------------------

__device__ __forceinline__ int bitrev8(int x) {
  x = ((x & 0x0F) << 4) | ((x >> 4) & 0x0F);
  x = ((x & 0x33) << 2) | ((x >> 2) & 0x33);
  x = ((x & 0x55) << 1) | ((x >> 1) & 0x55);
  return x;
}

__global__ __launch_bounds__(64)
void fft_rows(const float* __restrict__ x, float2* __restrict__ out) {
  __shared__ float2 s[256];
  __shared__ float2 tw[128];
  int blk = blockIdx.x;
  const float* rowp = x + (size_t)blk * 256;
  int t = threadIdx.x;
  for (int i = t; i < 128; i += 64) {
    float sn, cs;
    sincosf(-(PI2F / 256.f) * (float)i, &sn, &cs);
    tw[i] = make_float2(cs, sn);
  }
  #pragma unroll
  for (int e = 0; e < 4; ++e) {
    int i = t + (e << 6);
    s[bitrev8(i)] = make_float2(rowp[i], 0.f);
  }
  __syncthreads();
  #pragma unroll
  for (int st = 1; st <= 8; ++st) {
    int half = 1 << (st - 1);
    #pragma unroll
    for (int j = 0; j < 2; ++j) {
      int bf = t + (j << 6);
      int pos = bf & (half - 1);
      int grp = bf >> (st - 1);
      int i0 = (grp << st) | pos;
      int i1 = i0 + half;
      int k = pos << (8 - st);
      float cs = tw[k].x, sn = tw[k].y;
      float2 a = s[i0], b = s[i1];
      float tr = cs * b.x - sn * b.y;
      float ti = cs * b.y + sn * b.x;
      s[i0] = make_float2(a.x + tr, a.y + ti);
      s[i1] = make_float2(a.x - tr, a.y - ti);
    }
    __syncthreads();
  }
  float2* op = out + (size_t)blk * 256;
  #pragma unroll
  for (int e = 0; e < 4; ++e) { int i = t + (e << 6); op[i] = s[i]; }
}

__device__ __forceinline__ int radial_bin(int r2) {
  int j = (int)(sqrtf((float)r2) * 0.25f);
  while ((j + 1) * (j + 1) * 16 <= r2) ++j;
  while (j > 0 && j * j * 16 > r2) --j;
  return j;
}

__global__ __launch_bounds__(256)
void fft_cols_radial_v2(const float2* __restrict__ f, float* __restrict__ radial) {
  __shared__ float2 s[8][258];
  __shared__ float2 tw[128];
  __shared__ float bins[8][32];
  int b = blockIdx.x >> 5;
  int col0 = (blockIdx.x & 31) * 8;
  int t = threadIdx.x;
  for (int i = t; i < 128; i += 256) {
    float sn, cs;
    sincosf(-(PI2F / 256.f) * (float)i, &sn, &cs);
    tw[i] = make_float2(cs, sn);
  }
  ((float*)bins)[t] = 0.f;
  for (int idx = t; idx < 2048; idx += 256) {
    int row = idx >> 3, c = idx & 7;
    s[c][bitrev8(row)] = f[(size_t)b * 65536 + row * 256 + col0 + c];
  }
  __syncthreads();
  int c = t >> 5, l = t & 31;
  float2* sc = &s[c][0];
  #pragma unroll
  for (int st = 1; st <= 8; ++st) {
    int half = 1 << (st - 1);
    #pragma unroll
    for (int j = 0; j < 4; ++j) {
      int bf = l + (j << 5);
      int pos = bf & (half - 1);
      int grp = bf >> (st - 1);
      int i0 = (grp << st) | pos;
      int i1 = i0 + half;
      int k = pos << (8 - st);
      float cs = tw[k].x, sn = tw[k].y;
      float2 a = sc[i0], bb = sc[i1];
      float tr = cs * bb.x - sn * bb.y;
      float ti = cs * bb.y + sn * bb.x;
      sc[i0] = make_float2(a.x + tr, a.y + ti);
      sc[i1] = make_float2(a.x - tr, a.y - ti);
    }
    __syncthreads();
  }
  int dx = col0 + c - 128;
  #pragma unroll
  for (int e = 0; e < 8; ++e) {
    int i = l * 8 + e;
    float2 v = sc[i];
    float ps = v.x * v.x + v.y * v.y;
    int dy = i - 128;
    int r2 = dx * dx + dy * dy;
    if (r2 < 16384) atomicAdd(&bins[c][radial_bin(r2)], ps);
  }
  __syncthreads();
  if (t < 32) {
    float s0 = bins[0][t] + bins[1][t] + bins[2][t] + bins[3][t] +
               bins[4][t] + bins[5][t] + bins[6][t] + bins[7][t];
    atomicAdd(&radial[b * 32 + t], s0);
  }
}

__device__ __forceinline__ int isqrt_(int v) {
  int r = (int)sqrtf((float)v);
  while (r * r > v) --r;
  while ((r + 1) * (r + 1) <= v) ++r;
  return r;
}

__global__ __launch_bounds__(256)
void radial_finalize_v3(const float* __restrict__ radial, float* __restrict__ pf0) {
  __shared__ int red[4];
  __shared__ int cnt_s;
  int j = blockIdx.x, t = threadIdx.x;
  int dy = t - 128;
  int lo = 16 * j * j, hi = 16 * (j + 1) * (j + 1);
  int d2 = dy * dy;
  int cnt = 0;
  int tHi = hi - 1 - d2;
  if (tHi >= 0) {
    int rHi = isqrt_(tHi);
    int nHi = min(rHi, 127) + min(rHi, 128) + 1;
    int nLo = 0;
    int tLo = lo - 1 - d2;
    if (tLo >= 0) { int rLo = isqrt_(tLo); nLo = min(rLo, 127) + min(rLo, 128) + 1; }
    cnt = nHi - nLo;
  }
  #pragma unroll
  for (int off = 32; off > 0; off >>= 1) cnt += __shfl_down(cnt, off);
  if ((t & 63) == 0) red[t >> 6] = cnt;
  __syncthreads();
  if (t == 0) cnt_s = red[0] + red[1] + red[2] + red[3];
  __syncthreads();
  if (t < 16) {
    float cf = (float)cnt_s;
    float sum = radial[t * 32 + j];
    float val = cf > 0.f ? sum / fmaxf(cf, 1.f) : 0.f;
    pf0[t * 32 + j] = logf(val + 1e-10f);
  }
}

// ---------------- weight transforms -----------------------------------------

__global__ __launch_bounds__(256)
void wtrans_all(const float* __restrict__ cw2, const float* __restrict__ cw3,
                const float* __restrict__ cw4, const float* __restrict__ pcw,
                _Float16* __restrict__ wb2, _Float16* __restrict__ wb3,
                _Float16* __restrict__ wb4, _Float16* __restrict__ wbp) {
  int blk = blockIdx.x;
  const float* src; _Float16* dst; int COUT, CIN, KK, i;
  if (blk < 200)       { src = cw2; dst = wb2; COUT = 64;  CIN = 32;  KK = 25; i = blk * 256; }
  else if (blk < 488)  { src = cw3; dst = wb3; COUT = 128; CIN = 64;  KK = 9;  i = (blk - 200) * 256; }
  else if (blk < 1640) { src = cw4; dst = wb4; COUT = 256; CIN = 128; KK = 9;  i = (blk - 488) * 256; }
  else                 { src = pcw; dst = wbp; COUT = 128; CIN = 256; KK = 9;  i = (blk - 1640) * 256; }
  i += threadIdx.x;
  if (i >= COUT * CIN * KK) return;
  int ci = i % CIN;
  int r = i / CIN;
  int co = r % COUT;
  int tap = r / COUT;
  dst[i] = (_Float16)src[((size_t)co * CIN + ci) * KK + tap];
}

// ---------------- conv1 (Cin=1, 5x5): float4 register-window ----------------

__device__ __forceinline__ void load16(float* d, const float* p) {
  f32x4 v0 = *(const f32x4*)(p);
  f32x4 v1 = *(const f32x4*)(p + 4);
  f32x4 v2 = *(const f32x4*)(p + 8);
  f32x4 v3 = *(const f32x4*)(p + 12);
  #pragma unroll
  for (int e = 0; e < 4; ++e) { d[e] = v0[e]; d[4+e] = v1[e]; d[8+e] = v2[e]; d[12+e] = v3[e]; }
}

__global__ __launch_bounds__(256)
void conv1_stats_v3(const float* __restrict__ x, const float* __restrict__ w,
                    float* __restrict__ stats) {
  __shared__ float lds[12 * 264];
  __shared__ float r1[4][32], r2[4][32];
  int t = threadIdx.x;
  int y0 = blockIdx.x * 8, n = blockIdx.y;
  const float* xp = x + (size_t)n * 65536;
  for (int i = t; i < 12 * 264; i += 256) {
    int r = i / 264, cc = i % 264;
    int gy = y0 + r - 2, gx = cc - 4;
    lds[i] = (gy >= 0 && gy < 256 && gx >= 0 && gx < 256) ? xp[gy * 256 + gx] : 0.f;
  }
  __syncthreads();
  int c = t & 31, xg = t >> 5;
  float wreg[25];
  #pragma unroll
  for (int k = 0; k < 25; ++k) wreg[k] = w[c * 25 + k];
  float s1 = 0.f, s2 = 0.f;
  for (int strip = 0; strip < 4; ++strip) {
    int px0 = xg * 8 + strip * 64;
    float f[5][16];
    #pragma unroll
    for (int rr = 0; rr < 4; ++rr) load16(f[rr], &lds[rr * 264 + px0]);
    #pragma unroll
    for (int r = 0; r < 8; ++r) {
      load16(f[(r + 4) % 5], &lds[(r + 4) * 264 + px0]);
      f32x4 A = {0.f, 0.f, 0.f, 0.f}, B = {0.f, 0.f, 0.f, 0.f};
      #pragma unroll
      for (int ky = 0; ky < 5; ++ky) {
        const float* fr = f[(r + ky) % 5];
        #pragma unroll
        for (int kx = 0; kx < 5; ++kx) {
          float wv = wreg[ky * 5 + kx];
          f32x4 ia = {fr[2 + kx], fr[3 + kx], fr[4 + kx], fr[5 + kx]};
          f32x4 ib = {fr[6 + kx], fr[7 + kx], fr[8 + kx], fr[9 + kx]};
          A += wv * ia; B += wv * ib;
        }
      }
      s1 += A[0] + A[1] + A[2] + A[3] + B[0] + B[1] + B[2] + B[3];
      s2 += A[0]*A[0] + A[1]*A[1] + A[2]*A[2] + A[3]*A[3]
          + B[0]*B[0] + B[1]*B[1] + B[2]*B[2] + B[3]*B[3];
    }
  }
  s1 += __shfl_down(s1, 32);
  s2 += __shfl_down(s2, 32);
  if ((t & 63) < 32) { r1[t >> 6][t & 31] = s1; r2[t >> 6][t & 31] = s2; }
  __syncthreads();
  if (t < 32) {
    atomicAdd(&stats[t],      r1[0][t] + r1[1][t] + r1[2][t] + r1[3][t]);
    atomicAdd(&stats[32 + t], r2[0][t] + r2[1][t] + r2[2][t] + r2[3][t]);
  }
}

__global__ __launch_bounds__(256)
void conv1_apply_v3(const float* __restrict__ x, const float* __restrict__ w,
                    const float* __restrict__ stats, const float* __restrict__ g,
                    const float* __restrict__ bb, _Float16* __restrict__ pool1) {
  __shared__ float lds[6 * 264];
  int t = threadIdx.x;
  int py = blockIdx.x, n = blockIdx.y;
  const float* xp = x + (size_t)n * 65536;
  for (int i = t; i < 6 * 264; i += 256) {
    int r = i / 264, cc = i % 264;
    int gy = 2 * py + r - 2, gx = cc - 4;
    lds[i] = (gy >= 0 && gy < 256 && gx >= 0 && gx < 256) ? xp[gy * 256 + gx] : 0.f;
  }
  __syncthreads();
  int c = t & 31, xg = t >> 5;
  float wreg[25];
  #pragma unroll
  for (int k = 0; k < 25; ++k) wreg[k] = w[c * 25 + k];
  float mean = stats[c] * (1.f / 1048576.f);
  float var  = stats[32 + c] * (1.f / 1048576.f) - mean * mean;
  float sc = g[c] / sqrtf(var + 1e-5f);
  float sh = bb[c] - mean * sc;
  for (int iter = 0; iter < 4; ++iter) {
    int p0 = xg * 4 + iter * 32;
    float f[6][16];
    #pragma unroll
    for (int rr = 0; rr < 6; ++rr) load16(f[rr], &lds[rr * 264 + 2 * p0]);
    f32x4 acc[2][2];
    #pragma unroll
    for (int sy = 0; sy < 2; ++sy)
      #pragma unroll
      for (int h = 0; h < 2; ++h) acc[sy][h] = (f32x4){0.f, 0.f, 0.f, 0.f};
    #pragma unroll
    for (int sy = 0; sy < 2; ++sy)
      #pragma unroll
      for (int ky = 0; ky < 5; ++ky) {
        const float* fr = f[sy + ky];
        #pragma unroll
        for (int kx = 0; kx < 5; ++kx) {
          float wv = wreg[ky * 5 + kx];
          f32x4 ia = {fr[2 + kx], fr[3 + kx], fr[4 + kx], fr[5 + kx]};
          f32x4 ib = {fr[6 + kx], fr[7 + kx], fr[8 + kx], fr[9 + kx]};
          acc[sy][0] += wv * ia; acc[sy][1] += wv * ib;
        }
      }
    #pragma unroll
    for (int pp = 0; pp < 4; ++pp) {
      float v00 = acc[0][(2*pp) >> 2][(2*pp) & 3];
      float v01 = acc[0][(2*pp+1) >> 2][(2*pp+1) & 3];
      float v10 = acc[1][(2*pp) >> 2][(2*pp) & 3];
      float v11 = acc[1][(2*pp+1) >> 2][(2*pp+1) & 3];
      float m = fmaxf(fmaxf(v00, v01), fmaxf(v10, v11));
      pool1[(((size_t)n * 128 + py) * 128 + p0 + pp) * 32 + c] =
          (_Float16)fmaxf(m * sc + sh, 0.f);
    }
  }
}

// ---------------- single-K-slab implicit-GEMM MFMA conv ---------------------
// Stage SLAB ci of the whole spatial tile into LDS (1 barrier), then the full
// tap x cc MFMA loop reads B from LDS, A (weights) from global (L2-resident).
// stats: 8 atomic slices (blockIdx.x&7) summed by the BN epilogue.

template <int CIN, int COUT, int H, int W, int K, int TH, int TW, int COT,
          int PT, int SLAB>
__global__ __launch_bounds__(256)
void conv_mfma2(const _Float16* __restrict__ in, const _Float16* __restrict__ wb,
                _Float16* __restrict__ out, float* __restrict__ stats) {
  constexpr int P = K / 2, R = TH + 2 * P, XW = TW + 2 * P, PIX = R * XW;
  constexpr int TAPS = K * K, CSP = SLAB + 8;
  constexpr int NCC = SLAB / 32, NPH = CIN / SLAB, SUBS = SLAB / 8;
  static_assert(TH * TW == 32 * PT, "pos tile mismatch");
  __shared__ _Float16 lds[PIX * CSP];
  __shared__ float sst[2][32 * COT];
  int t = threadIdx.x;
  int lane = t & 63, wv = t >> 6;
  int lane15 = lane & 15, quad = lane >> 4;
  constexpr int WT = W / TW;
  int x0 = (blockIdx.x % WT) * TW, y0 = (blockIdx.x / WT) * TH;
  int coB = blockIdx.y * (32 * COT);
  int nb = blockIdx.z;
  int co_off = (wv & 1) * (16 * COT);
  int pos_off = (wv >> 1) * (16 * PT);

  for (int i = t; i < 64 * COT; i += 256) ((float*)sst)[i] = 0.f;

  f32x4 acc[COT][PT];
  #pragma unroll
  for (int ct = 0; ct < COT; ++ct)
    #pragma unroll
    for (int pt = 0; pt < PT; ++pt)
      #pragma unroll
      for (int e = 0; e < 4; ++e) acc[ct][pt][e] = 0.f;

  int bbase[PT];
  #pragma unroll
  for (int pt = 0; pt < PT; ++pt) {
    int np = pos_off + pt * 16 + lane15;
    int ly = np / TW, lx = np % TW;
    bbase[pt] = (ly * XW + lx) * CSP + quad * 8;
  }
  const _Float16* aptr[COT];
  #pragma unroll
  for (int ct = 0; ct < COT; ++ct)
    aptr[ct] = wb + (size_t)(coB + co_off + ct * 16 + lane15) * CIN + quad * 8;

  const _Float16* inb = in + (size_t)nb * H * W * CIN;

  #pragma unroll
  for (int ph = 0; ph < NPH; ++ph) {
    constexpr int ITEMS = PIX * SUBS;
    for (int i = t; i < ITEMS; i += 256) {
      int sub = i % SUBS, pix = i / SUBS;
      int r = pix / XW, xx = pix % XW;
      int gy = y0 + r - P, gx = x0 + xx - P;
      half8 v;
      #pragma unroll
      for (int j = 0; j < 8; ++j) v[j] = (_Float16)0.f;
      if (gy >= 0 && gy < H && gx >= 0 && gx < W)
        v = *(const half8*)(inb + ((size_t)gy * W + gx) * CIN + ph * SLAB + sub * 8);
      *(half8*)(&lds[pix * CSP + sub * 8]) = v;
    }
    __syncthreads();
    #pragma unroll
    for (int cc = 0; cc < NCC; ++cc) {
      #pragma unroll
      for (int tap = 0; tap < TAPS; ++tap) {
        int ky = tap / K, kx = tap % K;
        half8 a[COT], b[PT];
        #pragma unroll
        for (int ct = 0; ct < COT; ++ct)
          a[ct] = *(const half8*)(aptr[ct] + (size_t)tap * COUT * CIN +
                                  ph * SLAB + cc * 32);
        #pragma unroll
        for (int pt = 0; pt < PT; ++pt)
          b[pt] = *(const half8*)(&lds[bbase[pt] + (ky * XW + kx) * CSP + cc * 32]);
        #pragma unroll
        for (int ct = 0; ct < COT; ++ct)
          #pragma unroll
          for (int pt = 0; pt < PT; ++pt)
            acc[ct][pt] = __builtin_amdgcn_mfma_f32_16x16x32_f16(
                a[ct], b[pt], acc[ct][pt], 0, 0, 0);
      }
    }
    if (ph + 1 < NPH) __syncthreads();
  }

  #pragma unroll
  for (int ct = 0; ct < COT; ++ct)
    #pragma unroll
    for (int pt = 0; pt < PT; ++pt) {
      int co = coB + co_off + ct * 16 + quad * 4;
      int np = pos_off + pt * 16 + lane15;
      int y = y0 + np / TW, x = x0 + np % TW;
      _Float16* op = out + (((size_t)nb * H + y) * W + x) * COUT + co;
      half4v h;
      #pragma unroll
      for (int e = 0; e < 4; ++e) h[e] = (_Float16)acc[ct][pt][e];
      *(half4v*)op = h;
    }
  #pragma unroll
  for (int ct = 0; ct < COT; ++ct)
    #pragma unroll
    for (int e = 0; e < 4; ++e) {
      float sv = 0.f, sq = 0.f;
      #pragma unroll
      for (int pt = 0; pt < PT; ++pt) {
        float v = acc[ct][pt][e];
        sv += v; sq += v * v;
      }
      sv += __shfl_xor(sv, 1); sq += __shfl_xor(sq, 1);
      sv += __shfl_xor(sv, 2); sq += __shfl_xor(sq, 2);
      sv += __shfl_xor(sv, 4); sq += __shfl_xor(sq, 4);
      sv += __shfl_xor(sv, 8); sq += __shfl_xor(sq, 8);
      if (lane15 == 0) {
        int cl = co_off + ct * 16 + quad * 4 + e;
        atomicAdd(&sst[0][cl], sv);
        atomicAdd(&sst[1][cl], sq);
      }
    }
  __syncthreads();
  float* st = stats + (blockIdx.x & 7) * 2 * COUT;
  for (int i = t; i < 32 * COT; i += 256) {
    atomicAdd(&st[coB + i], sst[0][i]);
    atomicAdd(&st[COUT + coB + i], sst[1][i]);
  }
}

// ---------------- BN epilogues (sum 8 stat slices) --------------------------

__device__ __forceinline__ void bn_coeff(const float* stats, int C, int c,
                                         float invN, const float* g,
                                         const float* bb, float* sc, float* sh) {
  float s1 = 0.f, s2 = 0.f;
  #pragma unroll
  for (int s = 0; s < 8; ++s) {
    s1 += stats[s * 2 * C + c];
    s2 += stats[s * 2 * C + C + c];
  }
  float mean = s1 * invN;
  float var  = s2 * invN - mean * mean;
  float k = g[c] / sqrtf(var + 1e-5f);
  *sc = k; *sh = bb[c] - mean * k;
}

__global__ __launch_bounds__(256)
void bn_pool_nhwc(const _Float16* __restrict__ x, const float* __restrict__ stats,
                  const float* __restrict__ g, const float* __restrict__ bb,
                  _Float16* __restrict__ out, int C, int H, int W, float invN) {
  __shared__ float scs[256], shs[256];
  int t = threadIdx.x;
  int py = blockIdx.x, n = blockIdx.y;
  for (int c = t; c < C; c += 256) bn_coeff(stats, C, c, invN, g, bb, &scs[c], &shs[c]);
  __syncthreads();
  int W2 = W >> 1;
  int tot = W2 * C;
  for (int i = t; i < tot; i += 256) {
    int c = i % C, px = i / C;
    const _Float16* p0 = x + (((size_t)n * H + 2 * py) * W + 2 * px) * C + c;
    float sc = scs[c], sh = shs[c];
    float a = fmaxf((float)p0[0] * sc + sh, 0.f);
    float b = fmaxf((float)p0[C] * sc + sh, 0.f);
    float d = fmaxf((float)p0[(size_t)W * C] * sc + sh, 0.f);
    float e = fmaxf((float)p0[(size_t)W * C + C] * sc + sh, 0.f);
    out[(((size_t)n * (H / 2) + py) * W2 + px) * C + c] =
        (_Float16)fmaxf(fmaxf(a, b), fmaxf(d, e));
  }
}

__global__ __launch_bounds__(256)
void bn_relu_h16(const _Float16* __restrict__ x, const float* __restrict__ stats,
                 const float* __restrict__ g, const float* __restrict__ bb,
                 _Float16* __restrict__ out, int C, int HW, float invN) {
  __shared__ float scs[256], shs[256];
  int t = threadIdx.x;
  int n = blockIdx.y;
  for (int c = t; c < C; c += 256) bn_coeff(stats, C, c, invN, g, bb, &scs[c], &shs[c]);
  __syncthreads();
  int total = HW * C;
  int chunk = total / gridDim.x;
  int base = blockIdx.x * chunk;
  const _Float16* xp = x + (size_t)n * total;
  _Float16* op = out + (size_t)n * total;
  for (int i = base + t; i < base + chunk; i += 256) {
    int c = i % C;
    op[i] = (_Float16)fmaxf((float)xp[i] * scs[c] + shs[c], 0.f);
  }
}

__global__ __launch_bounds__(256)
void bn_avgpool_concat(const _Float16* __restrict__ x, const float* __restrict__ stats,
                       const float* __restrict__ g, const float* __restrict__ bb,
                       float* __restrict__ concat, float invN) {
  __shared__ float scs[128], shs[128];
  int t = threadIdx.x;
  int n = blockIdx.x;
  for (int c = t; c < 128; c += 256) bn_coeff(stats, 128, c, invN, g, bb, &scs[c], &shs[c]);
  __syncthreads();
  for (int i = t; i < 2048; i += 256) {
    int c = i & 127, opix = i >> 7;
    int py = opix >> 2, px = opix & 3;
    float sc = scs[c], sh = shs[c];
    float s = 0.f;
    for (int yy = 0; yy < 8; ++yy)
      for (int xx = 0; xx < 8; ++xx)
        s += fmaxf((float)x[(((size_t)n * 32 + py * 8 + yy) * 32 + px * 8 + xx) * 128 + c] * sc + sh, 0.f);
    concat[(size_t)n * 2112 + c * 16 + opix] = s * (1.f / 64.f);
  }
}

// ---------------- MLP heads -------------------------------------------------

__global__ __launch_bounds__(64)
void linear_k(const float* __restrict__ in, const float* __restrict__ w,
              const float* __restrict__ bias, float* __restrict__ out,
              int I, int in_stride, int out_stride, int relu) {
  int o = blockIdx.x, b = blockIdx.y;
  int lane = threadIdx.x;
  const float* ip = in + (size_t)b * in_stride;
  const float* wp = w + (size_t)o * I;
  float acc = 0.f;
  for (int i = lane; i < I; i += 64) acc += ip[i] * wp[i];
  #pragma unroll
  for (int off = 32; off > 0; off >>= 1) acc += __shfl_down(acc, off);
  if (lane == 0) {
    float v = acc + bias[o];
    if (relu) v = fmaxf(v, 0.f);
    out[(size_t)b * out_stride + o] = v;
  }
}

__global__ __launch_bounds__(256)
void pf_mlp(const float* __restrict__ pf0,
            const float* __restrict__ pw1, const float* __restrict__ pb1,
            const float* __restrict__ pw2, const float* __restrict__ pb2,
            const float* __restrict__ pw3, const float* __restrict__ pb3,
            float* __restrict__ concat) {
  __shared__ float a0[32], a1[256], a2[128];
  int b = blockIdx.x, t = threadIdx.x;
  if (t < 32) a0[t] = pf0[b * 32 + t];
  __syncthreads();
  {
    float s = pb1[t];
    for (int i = 0; i < 32; ++i) s += pw1[t * 32 + i] * a0[i];
    a1[t] = fmaxf(s, 0.f);
  }
  __syncthreads();
  if (t < 128) {
    float s = pb2[t];
    for (int i = 0; i < 256; ++i) s += pw2[t * 256 + i] * a1[i];
    a2[t] = fmaxf(s, 0.f);
  }
  __syncthreads();
  if (t < 64) {
    float s = pb3[t];
    for (int i = 0; i < 128; ++i) s += pw3[t * 128 + i] * a2[i];
    concat[(size_t)b * 2112 + 2048 + t] = fmaxf(s, 0.f);
  }
}

__global__ __launch_bounds__(256)
void fc_tail(const float* __restrict__ fc1o,
             const float* __restrict__ fw2, const float* __restrict__ fb2,
             const float* __restrict__ fw3, const float* __restrict__ fb3,
             const float* __restrict__ fw4, const float* __restrict__ fb4,
             float* __restrict__ out) {
  __shared__ float a1[512], a2[256], a3[128];
  int b = blockIdx.x, t = threadIdx.x;
  a1[t] = fc1o[b * 512 + t];
  a1[t + 256] = fc1o[b * 512 + t + 256];
  __syncthreads();
  {
    float s = fb2[t];
    for (int i = 0; i < 512; ++i) s += fw2[t * 512 + i] * a1[i];
    a2[t] = fmaxf(s, 0.f);
  }
  __syncthreads();
  if (t < 128) {
    float s = fb3[t];
    for (int i = 0; i < 256; ++i) s += fw3[t * 256 + i] * a2[i];
    a3[t] = fmaxf(s, 0.f);
  }
  __syncthreads();
  if (t < 2) {
    float s = fb4[t];
    for (int i = 0; i < 128; ++i) s += fw4[t * 128 + i] * a3[i];
    out[b * 2 + t] = s;
  }
}

// ---------------------------------------------------------------------------

extern "C" void kernel_launch(void* const* d_in, const int* in_sizes, int n_in,
                              void* d_out, int out_size, void* d_ws, size_t ws_size,
                              hipStream_t stream) {
  (void)in_sizes; (void)n_in; (void)out_size; (void)ws_size;
  const float* x   = (const float*)d_in[0];
  const float* cw1 = (const float*)d_in[1];
  const float* g1  = (const float*)d_in[3];
  const float* bb1 = (const float*)d_in[4];
  const float* cw2 = (const float*)d_in[5];
  const float* g2  = (const float*)d_in[7];
  const float* bb2 = (const float*)d_in[8];
  const float* cw3 = (const float*)d_in[9];
  const float* g3  = (const float*)d_in[11];
  const float* bb3 = (const float*)d_in[12];
  const float* cw4 = (const float*)d_in[13];
  const float* g4  = (const float*)d_in[15];
  const float* bb4 = (const float*)d_in[16];
  const float* pcw = (const float*)d_in[17];
  const float* pg  = (const float*)d_in[19];
  const float* pbb = (const float*)d_in[20];
  const float* pw1 = (const float*)d_in[21];
  const float* pb1 = (const float*)d_in[22];
  const float* pw2 = (const float*)d_in[23];
  const float* pb2 = (const float*)d_in[24];
  const float* pw3 = (const float*)d_in[25];
  const float* pb3 = (const float*)d_in[26];
  const float* fw1 = (const float*)d_in[27];
  const float* fb1 = (const float*)d_in[28];
  const float* fw2 = (const float*)d_in[29];
  const float* fb2 = (const float*)d_in[30];
  const float* fw3 = (const float*)d_in[31];
  const float* fb3 = (const float*)d_in[32];
  const float* fw4 = (const float*)d_in[33];
  const float* fb4 = (const float*)d_in[34];

  char* base = (char*)d_ws;
  float2*    fftbuf = (float2*)(base + 0);             // [16,256,256] cplx
  _Float16*  conv2o = (_Float16*)(base + 0);           // [16,128,128,64]
  _Float16*  conv3o = (_Float16*)(base + 0);           // [16,64,64,128]
  _Float16*  conv4o = (_Float16*)(base + 0);           // [16,32,32,256]
  _Float16*  pconvo = (_Float16*)(base + 16777216);    // [16,32,32,128]
  _Float16*  pool1  = (_Float16*)(base + 33554432);    // [16,128,128,32]
  _Float16*  pool2  = (_Float16*)(base + 50331648);    // [16,64,64,64]
  _Float16*  pool3  = (_Float16*)(base + 58720256);    // [16,32,32,128]
  _Float16*  act4   = (_Float16*)(base + 62914560);    // [16,32,32,256]
  _Float16*  wb2    = (_Float16*)(base + 71303168);
  _Float16*  wb3    = (_Float16*)(base + 71405568);
  _Float16*  wb4    = (_Float16*)(base + 71553024);
  _Float16*  wbp    = (_Float16*)(base + 72142848);
  // stats region: conv1 [2][32]; conv2..pconv are 8 slices of [2][C]; radial.
  float*     zbase  = (float*)(base + 72732672);
  float*     stats1 = zbase;                 // 64
  float*     stats2 = zbase + 64;            // 8*128  = 1024
  float*     stats3 = zbase + 1088;          // 8*256  = 2048
  float*     stats4 = zbase + 3136;          // 8*512  = 4096
  float*     stats5 = zbase + 7232;          // 8*256  = 2048
  float*     radial = zbase + 9280;          // 512
  float*     pf0    = (float*)(base + 72771840);
  float*     concat = (float*)(base + 72773888);       // 16*2112
  float*     fc1o   = (float*)(base + 72909056);

  hipMemsetAsync(zbase, 0, 9792 * sizeof(float), stream);

  wtrans_all<<<2792, 256, 0, stream>>>(cw2, cw3, cw4, pcw, wb2, wb3, wb4, wbp);

  // ---- FFT / power-features branch (fftbuf aliases conv region) ----
  fft_rows<<<4096, 64, 0, stream>>>(x, fftbuf);
  fft_cols_radial_v2<<<512, 256, 0, stream>>>(fftbuf, radial);
  radial_finalize_v3<<<32, 256, 0, stream>>>(radial, pf0);
  pf_mlp<<<16, 256, 0, stream>>>(pf0, pw1, pb1, pw2, pb2, pw3, pb3, concat);

  // ---- conv1 ----
  conv1_stats_v3<<<dim3(32, 16), 256, 0, stream>>>(x, cw1, stats1);
  conv1_apply_v3<<<dim3(128, 16), 256, 0, stream>>>(x, cw1, stats1, g1, bb1, pool1);

  // ---- conv2: 8x16 tile, full-K slab (LDS 19.2KB, 2048 blocks) ----
  conv_mfma2<32, 64, 128, 128, 5, 8, 16, 2, 4, 32>
      <<<dim3(128, 1, 16), 256, 0, stream>>>(pool1, wb2, conv2o, stats2);
  bn_pool_nhwc<<<dim3(64, 16), 256, 0, stream>>>(
      conv2o, stats2, g2, bb2, pool2, 64, 128, 128, 1.f / 262144.f);

  // ---- conv3: 8x16 tile, full-K slab (LDS 25.9KB, 512 blocks) ----
  conv_mfma2<64, 128, 64, 64, 3, 8, 16, 4, 4, 64>
      <<<dim3(32, 1, 16), 256, 0, stream>>>(pool2, wb3, conv3o, stats3);
  bn_pool_nhwc<<<dim3(32, 16), 256, 0, stream>>>(
      conv3o, stats3, g3, bb3, pool3, 128, 64, 64, 1.f / 65536.f);

  // ---- conv4: 4x16 tile, full-K slab (LDS 29.4KB, 1024 blocks) ----
  conv_mfma2<128, 256, 32, 32, 3, 4, 16, 2, 2, 128>
      <<<dim3(16, 4, 16), 256, 0, stream>>>(pool3, wb4, conv4o, stats4);
  bn_relu_h16<<<dim3(8, 16), 256, 0, stream>>>(
      conv4o, stats4, g4, bb4, act4, 256, 1024, 1.f / 16384.f);

  // ---- pconv: 4x16 tile, 2 x 128-ci slabs (LDS 29.4KB, 512 blocks) ----
  conv_mfma2<256, 128, 32, 32, 3, 4, 16, 2, 2, 128>
      <<<dim3(16, 2, 16), 256, 0, stream>>>(act4, wbp, pconvo, stats5);
  bn_avgpool_concat<<<16, 256, 0, stream>>>(pconvo, stats5, pg, pbb, concat, 1.f / 16384.f);

  // ---- classifier head ----
  linear_k<<<dim3(512, 16), 64, 0, stream>>>(concat, fw1, fb1, fc1o, 2112, 2112, 512, 1);
  fc_tail<<<16, 256, 0, stream>>>(fc1o, fw2, fb2, fw3, fb3, fw4, fb4, (float*)d_out);
}